// Round 3
// baseline (739.275 us; speedup 1.0000x reference)
//
#include <hip/hip_runtime.h>
#include <math.h>

typedef __attribute__((ext_vector_type(8))) short bf16x8;
typedef __attribute__((ext_vector_type(4))) float f32x4;
typedef __attribute__((ext_vector_type(4))) _Float16 f16x4;

// f32 += f16(lo/hi half of packed dword) * f32  -- exact, single VOP3P instr
#define FMAMIX_LO(acc, pk, s) \
    asm("v_fma_mix_f32 %0, %1, %2, %0 op_sel:[0,0,0] op_sel_hi:[1,0,0]" \
        : "+v"(acc) : "v"(pk), "v"(s))
#define FMAMIX_HI(acc, pk, s) \
    asm("v_fma_mix_f32 %0, %1, %2, %0 op_sel:[1,0,0] op_sel_hi:[1,0,0]" \
        : "+v"(acc) : "v"(pk), "v"(s))

__device__ __forceinline__ unsigned short f2bf(float f) {
    unsigned int u = __float_as_uint(f);
    unsigned int r = (u + 0x7FFF + ((u >> 16) & 1)) >> 16;  // RNE
    return (unsigned short)r;
}
__device__ __forceinline__ float bf2f(unsigned short h) {
    return __uint_as_float((unsigned int)h << 16);
}
__device__ __forceinline__ void split_bf(float x, unsigned short& hi, unsigned short& lo) {
    hi = f2bf(x);
    lo = f2bf(x - bf2f(hi));
}

// ---------------- CSR build ----------------

__global__ void k_hist(const int* __restrict__ dst, int* __restrict__ deg, int e) {
    int t = blockIdx.x * 256 + threadIdx.x;
    if (t < e) atomicAdd(&deg[dst[t]], 1);
}

__global__ void k_scan1(const int* __restrict__ deg, int* __restrict__ tmp,
                        int* __restrict__ bsum, int n) {
    __shared__ int s[1024];
    int t = threadIdx.x;
    int g = blockIdx.x * 1024 + t;
    int v = (g < n) ? deg[g] : 0;
    s[t] = v;
    __syncthreads();
    for (int off = 1; off < 1024; off <<= 1) {
        int u = (t >= off) ? s[t - off] : 0;
        __syncthreads();
        s[t] += u;
        __syncthreads();
    }
    if (g < n) tmp[g] = s[t];
    if (t == 1023) bsum[blockIdx.x] = s[t];
}

__global__ void k_scan2(int* bsum, int nb) {
    int acc = 0;
    for (int b = 0; b < nb; ++b) { int v = bsum[b]; bsum[b] = acc; acc += v; }
}

__global__ void k_scan3(const int* __restrict__ deg, const int* __restrict__ tmp,
                        const int* __restrict__ bsum, int* __restrict__ rowptr,
                        int* __restrict__ cursor, int n) {
    int g = blockIdx.x * 256 + threadIdx.x;
    if (g < n) {
        int incl = tmp[g] + bsum[g >> 10];
        rowptr[g + 1] = incl;
        cursor[g] = incl - deg[g];
        if (g == 0) rowptr[0] = 0;
    }
}

__global__ void k_scatter(const int* __restrict__ src, const int* __restrict__ dst,
                          int* __restrict__ cursor, int* __restrict__ csr, int e) {
    int t = blockIdx.x * 256 + threadIdx.x;
    if (t < e) {
        int d = dst[t];
        int pos = atomicAdd(&cursor[d], 1);
        csr[pos] = src[t];
    }
}

// ---------------- casts (split hi/lo) ----------------

__global__ void k_castx(const float* __restrict__ x, unsigned short* __restrict__ xhi,
                        unsigned short* __restrict__ xlo, int nvec) {
    int t = blockIdx.x * 256 + threadIdx.x;
    if (t < nvec) {
        float4 v = ((const float4*)x)[t];
        ushort4 h, l;
        split_bf(v.x, h.x, l.x);
        split_bf(v.y, h.y, l.y);
        split_bf(v.z, h.z, l.z);
        split_bf(v.w, h.w, l.w);
        ((ushort4*)xhi)[t] = h;
        ((ushort4*)xlo)[t] = l;
    }
}

__global__ void k_castw(const float* __restrict__ W, unsigned short* __restrict__ Whi,
                        unsigned short* __restrict__ Wlo, int K, int N) {
    int t = blockIdx.x * 256 + threadIdx.x;
    if (t < K * N) {
        int k = t / N, n = t - k * N;
        unsigned short h, l;
        split_bf(W[t], h, l);
        Whi[n * K + k] = h; Wlo[n * K + k] = l;
    }
}

// ------- split-bf16 MFMA GEMM (NT): C = A @ Bt^T, ~fp32 accuracy ----------
// Output written as fp16 (feeds gathers in agg; 11-bit mantissa is enough).

#define LDP 40

// 64x64-tile kernel (small N: 64, 40)
__global__ __launch_bounds__(256) void k_gemm_split(const unsigned short* __restrict__ Ahi,
                                                    const unsigned short* __restrict__ Alo,
                                                    const unsigned short* __restrict__ Bhi,
                                                    const unsigned short* __restrict__ Blo,
                                                    _Float16* __restrict__ C,
                                                    int M, int Ncol, int K) {
    int bx = blockIdx.x, by = blockIdx.y;
    __shared__ unsigned short Ash[64 * LDP];
    __shared__ unsigned short Asl[64 * LDP];
    __shared__ unsigned short Bsh[64 * LDP];
    __shared__ unsigned short Bsl[64 * LDP];
    int t = threadIdx.x;
    int w = t >> 6, lane = t & 63;
    int lrow = lane & 15, kgrp = (lane >> 4) * 8;
    int row0 = bx * 64, col0 = by * 64;
    int trow = t >> 2, tcol = (t & 3) * 8;

    f32x4 acc[4] = {{0.f, 0.f, 0.f, 0.f}, {0.f, 0.f, 0.f, 0.f},
                    {0.f, 0.f, 0.f, 0.f}, {0.f, 0.f, 0.f, 0.f}};

    for (int k0 = 0; k0 < K; k0 += 32) {
        uint4 ah = {0u,0u,0u,0u}, al = {0u,0u,0u,0u};
        uint4 bh = {0u,0u,0u,0u}, bl = {0u,0u,0u,0u};
        int gr = row0 + trow;
        if (gr < M) {
            ah = *(const uint4*)(Ahi + (size_t)gr * K + k0 + tcol);
            al = *(const uint4*)(Alo + (size_t)gr * K + k0 + tcol);
        }
        int gc = col0 + trow;
        if (gc < Ncol) {
            bh = *(const uint4*)(Bhi + (size_t)gc * K + k0 + tcol);
            bl = *(const uint4*)(Blo + (size_t)gc * K + k0 + tcol);
        }
        __syncthreads();
        *(uint4*)&Ash[trow * LDP + tcol] = ah;
        *(uint4*)&Asl[trow * LDP + tcol] = al;
        *(uint4*)&Bsh[trow * LDP + tcol] = bh;
        *(uint4*)&Bsl[trow * LDP + tcol] = bl;
        __syncthreads();
        bf16x8 vbh = *(const bf16x8*)&Bsh[(w * 16 + lrow) * LDP + kgrp];
        bf16x8 vbl = *(const bf16x8*)&Bsl[(w * 16 + lrow) * LDP + kgrp];
        #pragma unroll
        for (int mt = 0; mt < 4; ++mt) {
            bf16x8 vah = *(const bf16x8*)&Ash[(mt * 16 + lrow) * LDP + kgrp];
            bf16x8 val = *(const bf16x8*)&Asl[(mt * 16 + lrow) * LDP + kgrp];
            acc[mt] = __builtin_amdgcn_mfma_f32_16x16x32_bf16(vah, vbh, acc[mt], 0, 0, 0);
            acc[mt] = __builtin_amdgcn_mfma_f32_16x16x32_bf16(val, vbh, acc[mt], 0, 0, 0);
            acc[mt] = __builtin_amdgcn_mfma_f32_16x16x32_bf16(vah, vbl, acc[mt], 0, 0, 0);
        }
    }

    int ocol = col0 + w * 16 + lrow;
    if (ocol < Ncol) {
        int orow = (lane >> 4) * 4;
        #pragma unroll
        for (int mt = 0; mt < 4; ++mt) {
            #pragma unroll
            for (int r = 0; r < 4; ++r) {
                int m = row0 + mt * 16 + orow + r;
                if (m < M) C[(size_t)m * Ncol + ocol] = (_Float16)acc[mt][r];
            }
        }
    }
}

// 128x128-tile kernel for Ncol==256 (2 col-blocks). 4 waves in 2x2 quadrants,
// 48 MFMA / wave / K-step. Bijective m204 XCD-chunk swizzle.
__global__ __launch_bounds__(256) void k_gemm128(const unsigned short* __restrict__ Ahi,
                                                 const unsigned short* __restrict__ Alo,
                                                 const unsigned short* __restrict__ Bhi,
                                                 const unsigned short* __restrict__ Blo,
                                                 _Float16* __restrict__ C,
                                                 int M, int Ncol, int K) {
    int Mb = (M + 127) >> 7;
    int nwg = Mb * 2;
    int v = blockIdx.x;
    int q = nwg >> 3, r = nwg & 7;
    int xcd = v & 7, idx = v >> 3;
    int wg = (xcd < r ? xcd * (q + 1) : r * (q + 1) + (xcd - r) * q) + idx;
    int bx = wg >> 1, by = wg & 1;
    int row0 = bx * 128, col0 = by * 128;

    __shared__ unsigned short Ash[128 * LDP];
    __shared__ unsigned short Asl[128 * LDP];
    __shared__ unsigned short Bsh[128 * LDP];
    __shared__ unsigned short Bsl[128 * LDP];

    int t = threadIdx.x;
    int w = t >> 6, lane = t & 63;
    int wr = w >> 1, wc = w & 1;
    int lrow = lane & 15, kgrp = (lane >> 4) * 8;
    int trow = t >> 1, tcol = (t & 1) * 16;

    f32x4 acc[4][4];
    #pragma unroll
    for (int mt = 0; mt < 4; ++mt)
        #pragma unroll
        for (int nt = 0; nt < 4; ++nt)
            acc[mt][nt] = (f32x4){0.f, 0.f, 0.f, 0.f};

    for (int k0 = 0; k0 < K; k0 += 32) {
        uint4 a0 = {0u,0u,0u,0u}, a1 = {0u,0u,0u,0u};
        uint4 l0 = {0u,0u,0u,0u}, l1 = {0u,0u,0u,0u};
        uint4 b0 = {0u,0u,0u,0u}, b1 = {0u,0u,0u,0u};
        uint4 m0 = {0u,0u,0u,0u}, m1 = {0u,0u,0u,0u};
        int gr = row0 + trow;
        if (gr < M) {
            const unsigned short* pa = Ahi + (size_t)gr * K + k0 + tcol;
            const unsigned short* pl = Alo + (size_t)gr * K + k0 + tcol;
            a0 = *(const uint4*)pa;       a1 = *(const uint4*)(pa + 8);
            l0 = *(const uint4*)pl;       l1 = *(const uint4*)(pl + 8);
        }
        int gc = col0 + trow;
        if (gc < Ncol) {
            const unsigned short* pb = Bhi + (size_t)gc * K + k0 + tcol;
            const unsigned short* pm = Blo + (size_t)gc * K + k0 + tcol;
            b0 = *(const uint4*)pb;       b1 = *(const uint4*)(pb + 8);
            m0 = *(const uint4*)pm;       m1 = *(const uint4*)(pm + 8);
        }
        __syncthreads();
        *(uint4*)&Ash[trow * LDP + tcol]     = a0;
        *(uint4*)&Ash[trow * LDP + tcol + 8] = a1;
        *(uint4*)&Asl[trow * LDP + tcol]     = l0;
        *(uint4*)&Asl[trow * LDP + tcol + 8] = l1;
        *(uint4*)&Bsh[trow * LDP + tcol]     = b0;
        *(uint4*)&Bsh[trow * LDP + tcol + 8] = b1;
        *(uint4*)&Bsl[trow * LDP + tcol]     = m0;
        *(uint4*)&Bsl[trow * LDP + tcol + 8] = m1;
        __syncthreads();

        bf16x8 vbh[4], vbl[4];
        #pragma unroll
        for (int nt = 0; nt < 4; ++nt) {
            vbh[nt] = *(const bf16x8*)&Bsh[(wc * 64 + nt * 16 + lrow) * LDP + kgrp];
            vbl[nt] = *(const bf16x8*)&Bsl[(wc * 64 + nt * 16 + lrow) * LDP + kgrp];
        }
        #pragma unroll
        for (int mt = 0; mt < 4; ++mt) {
            bf16x8 vah = *(const bf16x8*)&Ash[(wr * 64 + mt * 16 + lrow) * LDP + kgrp];
            bf16x8 val = *(const bf16x8*)&Asl[(wr * 64 + mt * 16 + lrow) * LDP + kgrp];
            #pragma unroll
            for (int nt = 0; nt < 4; ++nt) {
                acc[mt][nt] = __builtin_amdgcn_mfma_f32_16x16x32_bf16(vah, vbh[nt], acc[mt][nt], 0, 0, 0);
                acc[mt][nt] = __builtin_amdgcn_mfma_f32_16x16x32_bf16(val, vbh[nt], acc[mt][nt], 0, 0, 0);
                acc[mt][nt] = __builtin_amdgcn_mfma_f32_16x16x32_bf16(vah, vbl[nt], acc[mt][nt], 0, 0, 0);
            }
        }
    }

    int orow = (lane >> 4) * 4;
    #pragma unroll
    for (int mt = 0; mt < 4; ++mt) {
        #pragma unroll
        for (int nt = 0; nt < 4; ++nt) {
            int oc = col0 + wc * 64 + nt * 16 + lrow;
            #pragma unroll
            for (int rr = 0; rr < 4; ++rr) {
                int m = row0 + wr * 64 + mt * 16 + orow + rr;
                if (m < M) C[(size_t)m * Ncol + oc] = (_Float16)acc[mt][nt][rr];
            }
        }
    }
}

static inline void gemm_split(const unsigned short* Ah, const unsigned short* Al,
                              const unsigned short* Bh, const unsigned short* Bl,
                              _Float16* C, int M, int Ncol, int K, hipStream_t st) {
    if (Ncol == 256) {
        int Mb = (M + 127) / 128;
        k_gemm128<<<Mb * 2, 256, 0, st>>>(Ah, Al, Bh, Bl, C, M, Ncol, K);
    } else {
        int Mb = (M + 63) / 64, Nb = (Ncol + 63) / 64;
        k_gemm_split<<<dim3(Mb, Nb), 256, 0, st>>>(Ah, Al, Bh, Bl, C, M, Ncol, K);
    }
}

// ---------------- attention scores: el/er [N,H] ----------------

template <int H, int D>
__global__ __launch_bounds__(256) void k_attn(const _Float16* __restrict__ feat,
                                              const float* __restrict__ al,
                                              const float* __restrict__ ar,
                                              float* __restrict__ el,
                                              float* __restrict__ er, int n) {
    int gw = blockIdx.x * 4 + (threadIdx.x >> 6);
    int lane = threadIdx.x & 63;
    int i = gw / H, h = gw % H;
    if (i >= n) return;
    float f = (lane < D) ? (float)feat[i * (H * D) + h * D + lane] : 0.f;
    float wl = (lane < D) ? al[h * D + lane] : 0.f;
    float wr = (lane < D) ? ar[h * D + lane] : 0.f;
    float pl = f * wl, pr = f * wr;
    #pragma unroll
    for (int off = 32; off; off >>= 1) {
        pl += __shfl_xor(pl, off);
        pr += __shfl_xor(pr, off);
    }
    if (lane == 0) {
        el[i * H + h] = pl;
        er[i * H + h] = pr;
    }
}

__device__ __forceinline__ float lrelu(float v) { return v > 0.f ? v : 0.2f * v; }

// ---------------- H=4 aggregation: ONE WAVE per dst node ------------------
// Per 16-edge chunk: csr -> issue ALL 16 feat gathers into registers
// (readlane-broadcast src indices) -> prefetch next chunk's csr -> el gather
// + shfl-max + exp (hidden under the 16 in-flight loads) -> fma_mix consume
// from registers. Invalid edges clamp to row 0 (L1-resident) with alpha=0.
#define A4_ISSUE(J) uint2 q##J = *(const uint2*)(featLane + ((size_t)(unsigned)__shfl(s, (J) << 2) << 9))
#define A4_CONS(J, X) \
    FMAMIX_LO(a0, q##J.x, X); FMAMIX_HI(a1, q##J.x, X); \
    FMAMIX_LO(a2, q##J.y, X); FMAMIX_HI(a3, q##J.y, X)

template <int ACT, int SPLITOUT>
__global__ __launch_bounds__(256) void k_agg4(const int* __restrict__ rowptr,
                                              const int* __restrict__ csr,
                                              const float* __restrict__ el,
                                              const float* __restrict__ er,
                                              const _Float16* __restrict__ feat,
                                              unsigned short* __restrict__ ohi,
                                              unsigned short* __restrict__ olo,
                                              float* __restrict__ ofp, int n) {
    __shared__ float s_ex[4][64];
    int w = threadIdx.x >> 6;
    int lane = threadIdx.x & 63;
    int i = blockIdx.x * 4 + w;
    if (i >= n) return;
    int s0 = rowptr[i], s1 = rowptr[i + 1];
    int deg = s1 - s0;
    int eidx = lane >> 2, h = lane & 3;  // exp-stage role
    int hh = lane >> 4;                  // FMA/output-stage head
    float erh = er[i * 4 + h];
    const char* featLane = (const char*)feat + (lane << 3);

    float den = 0.f;
    float a0 = 0.f, a1 = 0.f, a2 = 0.f, a3 = 0.f;
    float m = -INFINITY;

    int e0 = s0 + eidx;
    int s = (e0 < s1) ? csr[e0] : 0;
    for (int c = s0; c < s1; c += 16) {
        bool val = (c + eidx < s1);
        // critical-chain load first (softmax depends on it)
        float elv = el[(s << 2) + h];
        // 16 feat gathers into registers (stay in flight across the exp chain)
        A4_ISSUE(0);  A4_ISSUE(1);  A4_ISSUE(2);  A4_ISSUE(3);
        A4_ISSUE(4);  A4_ISSUE(5);  A4_ISSUE(6);  A4_ISSUE(7);
        A4_ISSUE(8);  A4_ISSUE(9);  A4_ISSUE(10); A4_ISSUE(11);
        A4_ISSUE(12); A4_ISSUE(13); A4_ISSUE(14); A4_ISSUE(15);
        // prefetch next chunk's csr
        int en = c + 16 + eidx;
        int sn = (en < s1) ? csr[en] : 0;
        // online-softmax chain (overlaps the gathers)
        float v = val ? lrelu(elv + erh) : -INFINITY;
        float cm = v;
        #pragma unroll
        for (int off = 4; off < 64; off <<= 1) cm = fmaxf(cm, __shfl_xor(cm, off));
        float mn = fmaxf(m, cm);
        float scale = __expf(m - mn);  // 1.0 once max settles; 0 on first chunk
        m = mn;
        float ex = val ? __expf(v - mn) : 0.f;
        den = den * scale + ex;
        s_ex[w][(h << 4) + eidx] = ex;
        float scl = __shfl(scale, hh);  // lanes 0..3 hold h=0..3
        a0 *= scl; a1 *= scl; a2 *= scl; a3 *= scl;
        // consume
        const float* exrow = &s_ex[w][hh << 4];
        float4 x0 = *(const float4*)&exrow[0];
        float4 x1 = *(const float4*)&exrow[4];
        float4 x2 = *(const float4*)&exrow[8];
        float4 x3 = *(const float4*)&exrow[12];
        A4_CONS(0, x0.x);  A4_CONS(1, x0.y);  A4_CONS(2, x0.z);  A4_CONS(3, x0.w);
        A4_CONS(4, x1.x);  A4_CONS(5, x1.y);  A4_CONS(6, x1.z);  A4_CONS(7, x1.w);
        A4_CONS(8, x2.x);  A4_CONS(9, x2.y);  A4_CONS(10, x2.z); A4_CONS(11, x2.w);
        A4_CONS(12, x3.x); A4_CONS(13, x3.y); A4_CONS(14, x3.z); A4_CONS(15, x3.w);
        s = sn;
    }

    #pragma unroll
    for (int off = 4; off < 64; off <<= 1) den += __shfl_xor(den, off);
    float d = fmaxf(__shfl(den, hh), 1e-9f);

    float o0 = (deg > 0) ? a0 / d : 0.f;
    float o1 = (deg > 0) ? a1 / d : 0.f;
    float o2 = (deg > 0) ? a2 / d : 0.f;
    float o3 = (deg > 0) ? a3 / d : 0.f;
    if (ACT == 1) {
        o0 = o0 > 0.f ? o0 : (__expf(o0) - 1.f);
        o1 = o1 > 0.f ? o1 : (__expf(o1) - 1.f);
        o2 = o2 > 0.f ? o2 : (__expf(o2) - 1.f);
        o3 = o3 > 0.f ? o3 : (__expf(o3) - 1.f);
    }
    size_t base = (size_t)i * 256 + (lane << 2);
    if (SPLITOUT) {
        ushort4 vh, vl;
        split_bf(o0, vh.x, vl.x);
        split_bf(o1, vh.y, vl.y);
        split_bf(o2, vh.z, vl.z);
        split_bf(o3, vh.w, vl.w);
        *(ushort4*)&ohi[base] = vh;
        *(ushort4*)&olo[base] = vl;
    } else {
        float4 vo = {o0, o1, o2, o3};
        *(float4*)&ofp[base] = vo;
    }
}

// ---------------- H=1 aggregation (register-staged gather groups) ----------
// 64-edge chunks; exp stage 64-wide; FMA consume in 16-edge register groups
// with a 2-deep issue/consume pipeline.

#define A1_LD(G, J) unsigned q##G##_##J = (unsigned)*(const unsigned short*)( \
    featLane + (size_t)((unsigned)__shfl(s, (G) * 16 + (J)) * (unsigned)(D * 2)))
#define A1_ISSUE(G) \
    A1_LD(G,0);  A1_LD(G,1);  A1_LD(G,2);  A1_LD(G,3); \
    A1_LD(G,4);  A1_LD(G,5);  A1_LD(G,6);  A1_LD(G,7); \
    A1_LD(G,8);  A1_LD(G,9);  A1_LD(G,10); A1_LD(G,11); \
    A1_LD(G,12); A1_LD(G,13); A1_LD(G,14); A1_LD(G,15)
#define A1_CONS(G) { \
    const float* xr = &s_ex[w][(G) * 16]; \
    float4 xa = *(const float4*)&xr[0]; \
    float4 xb = *(const float4*)&xr[4]; \
    float4 xc = *(const float4*)&xr[8]; \
    float4 xd = *(const float4*)&xr[12]; \
    FMAMIX_LO(acc, q##G##_0, xa.x);  FMAMIX_LO(acc, q##G##_1, xa.y); \
    FMAMIX_LO(acc, q##G##_2, xa.z);  FMAMIX_LO(acc, q##G##_3, xa.w); \
    FMAMIX_LO(acc, q##G##_4, xb.x);  FMAMIX_LO(acc, q##G##_5, xb.y); \
    FMAMIX_LO(acc, q##G##_6, xb.z);  FMAMIX_LO(acc, q##G##_7, xb.w); \
    FMAMIX_LO(acc, q##G##_8, xc.x);  FMAMIX_LO(acc, q##G##_9, xc.y); \
    FMAMIX_LO(acc, q##G##_10, xc.z); FMAMIX_LO(acc, q##G##_11, xc.w); \
    FMAMIX_LO(acc, q##G##_12, xd.x); FMAMIX_LO(acc, q##G##_13, xd.y); \
    FMAMIX_LO(acc, q##G##_14, xd.z); FMAMIX_LO(acc, q##G##_15, xd.w); }

template <int D, int ACT, int SPLITOUT>
__global__ __launch_bounds__(256) void k_agg1(const int* __restrict__ rowptr,
                                              const int* __restrict__ csr,
                                              const float* __restrict__ el,
                                              const float* __restrict__ er,
                                              const _Float16* __restrict__ feat,
                                              unsigned short* __restrict__ ohi,
                                              unsigned short* __restrict__ olo,
                                              float* __restrict__ ofp, int n) {
    __shared__ float s_ex[4][64];
    int w = threadIdx.x >> 6;
    int i = blockIdx.x * 4 + w;
    int lane = threadIdx.x & 63;
    if (i >= n) return;
    int s0 = rowptr[i], s1 = rowptr[i + 1];
    int deg = s1 - s0;
    float eri = er[i];
    bool act = lane < D;
    const char* featLane = (const char*)feat + lane * 2;

    float den = 0.f, acc = 0.f, m = -INFINITY;

    int e0 = s0 + lane;
    int s = (e0 < s1) ? csr[e0] : 0;
    for (int c = s0; c < s1; c += 64) {
        bool val = (c + lane < s1);
        float elv = el[s];
        // prefetch next chunk's csr
        int en = c + 64 + lane;
        int sn = (en < s1) ? csr[en] : 0;
        float v = val ? lrelu(elv + eri) : -INFINITY;
        float cm = v;
        #pragma unroll
        for (int off = 32; off; off >>= 1) cm = fmaxf(cm, __shfl_xor(cm, off));
        float mn = fmaxf(m, cm);
        float scale = __expf(m - mn);
        m = mn;
        float ex = val ? __expf(v - mn) : 0.f;
        den = den * scale + ex;
        acc *= scale;
        s_ex[w][lane] = ex;
        int cnt = min(64, s1 - c);
        // 16-edge register groups, 2-deep pipeline (wave-uniform branches)
        A1_ISSUE(0);
        if (cnt > 16) {
            A1_ISSUE(1);
            A1_CONS(0);
            if (cnt > 32) {
                A1_ISSUE(2);
                A1_CONS(1);
                if (cnt > 48) {
                    A1_ISSUE(3);
                    A1_CONS(2);
                    A1_CONS(3);
                } else { A1_CONS(2); }
            } else { A1_CONS(1); }
        } else { A1_CONS(0); }
        s = sn;
    }
    #pragma unroll
    for (int off = 32; off; off >>= 1) den += __shfl_xor(den, off);

    float o = (deg > 0) ? acc / fmaxf(den, 1e-9f) : 0.f;
    if (ACT == 1) o = o > 0.f ? o : (__expf(o) - 1.f);
    if (act) {
        if (SPLITOUT) {
            unsigned short oh, ol;
            split_bf(o, oh, ol);
            ohi[(size_t)i * D + lane] = oh;
            olo[(size_t)i * D + lane] = ol;
        } else {
            ofp[(size_t)i * D + lane] = o;
        }
    }
}

// ---------------- launch ----------------

extern "C" void kernel_launch(void* const* d_in, const int* in_sizes, int n_in,
                              void* d_out, int out_size, void* d_ws, size_t ws_size,
                              hipStream_t stream) {
    const float* x    = (const float*)d_in[0];
    const int*   src  = (const int*)d_in[1];
    const int*   dst  = (const int*)d_in[2];
    const float* W00  = (const float*)d_in[3];
    const float* a00l = (const float*)d_in[4];
    const float* a00r = (const float*)d_in[5];
    const float* W01  = (const float*)d_in[6];
    const float* a01l = (const float*)d_in[7];
    const float* a01r = (const float*)d_in[8];
    const float* W0f  = (const float*)d_in[9];
    const float* a0fl = (const float*)d_in[10];
    const float* a0fr = (const float*)d_in[11];
    const float* W10  = (const float*)d_in[12];
    const float* a10l = (const float*)d_in[13];
    const float* a10r = (const float*)d_in[14];
    const float* W1f  = (const float*)d_in[15];
    const float* a1fl = (const float*)d_in[16];
    const float* a1fr = (const float*)d_in[17];
    const float* W1o  = (const float*)d_in[18];
    const float* a1ol = (const float*)d_in[19];
    const float* a1or = (const float*)d_in[20];
    float* out = (float*)d_out;

    const int n = in_sizes[0] / 256;  // 50000
    const int e = in_sizes[1];        // 800000
    const int C = 40;

    char* p = (char*)d_ws;
    auto alloc = [&](size_t bytes) -> void* {
        void* r = (void*)p;
        p += (bytes + 255) & ~(size_t)255;
        return r;
    };
    int*   deg     = (int*)alloc((size_t)n * 4);
    int*   tmp     = (int*)alloc((size_t)n * 4);
    int*   bsum    = (int*)alloc(64 * 4);
    int*   rowptr  = (int*)alloc((size_t)(n + 1) * 4);
    int*   cursor  = (int*)alloc((size_t)n * 4);
    int*   csr     = (int*)alloc((size_t)e * 4);
    float* el      = (float*)alloc((size_t)n * 4 * 4);
    float* er      = (float*)alloc((size_t)n * 4 * 4);
    _Float16* feat = (_Float16*)alloc((size_t)n * 256 * 2 + 256);
    unsigned short* xhi = (unsigned short*)alloc((size_t)n * 256 * 2);
    unsigned short* xlo = (unsigned short*)alloc((size_t)n * 256 * 2);
    unsigned short* hhi = (unsigned short*)alloc((size_t)n * 256 * 2);
    unsigned short* hlo = (unsigned short*)alloc((size_t)n * 256 * 2);
    unsigned short* W00h = (unsigned short*)alloc(256 * 256 * 2);
    unsigned short* W00l = (unsigned short*)alloc(256 * 256 * 2);
    unsigned short* W01h = (unsigned short*)alloc(256 * 64 * 2);
    unsigned short* W01l = (unsigned short*)alloc(256 * 64 * 2);
    unsigned short* W0fh = (unsigned short*)alloc(64 * 40 * 2);
    unsigned short* W0fl = (unsigned short*)alloc(64 * 40 * 2);
    unsigned short* W10h = (unsigned short*)alloc(256 * 256 * 2);
    unsigned short* W10l = (unsigned short*)alloc(256 * 256 * 2);
    unsigned short* W1fh = (unsigned short*)alloc(256 * 64 * 2);
    unsigned short* W1fl = (unsigned short*)alloc(256 * 64 * 2);
    unsigned short* W1oh = (unsigned short*)alloc(64 * 40 * 2);
    unsigned short* W1ol = (unsigned short*)alloc(64 * 40 * 2);

    // ---- CSR build ----
    hipMemsetAsync(deg, 0, (size_t)n * 4, stream);
    k_hist<<<(e + 255) / 256, 256, 0, stream>>>(dst, deg, e);
    int nb = (n + 1023) / 1024;
    k_scan1<<<nb, 1024, 0, stream>>>(deg, tmp, bsum, n);
    k_scan2<<<1, 1, 0, stream>>>(bsum, nb);
    k_scan3<<<(n + 255) / 256, 256, 0, stream>>>(deg, tmp, bsum, rowptr, cursor, n);
    k_scatter<<<(e + 255) / 256, 256, 0, stream>>>(src, dst, cursor, csr, e);

    // ---- casts ----
    int nel = n * 256;
    k_castx<<<(nel / 4 + 255) / 256, 256, 0, stream>>>(x, xhi, xlo, nel / 4);
    k_castw<<<(256 * 256 + 255) / 256, 256, 0, stream>>>(W00, W00h, W00l, 256, 256);
    k_castw<<<(256 * 64 + 255) / 256, 256, 0, stream>>>(W01, W01h, W01l, 256, 64);
    k_castw<<<(64 * 40 + 255) / 256, 256, 0, stream>>>(W0f, W0fh, W0fl, 64, 40);
    k_castw<<<(256 * 256 + 255) / 256, 256, 0, stream>>>(W10, W10h, W10l, 256, 256);
    k_castw<<<(256 * 64 + 255) / 256, 256, 0, stream>>>(W1f, W1fh, W1fl, 256, 64);
    k_castw<<<(64 * 40 + 255) / 256, 256, 0, stream>>>(W1o, W1oh, W1ol, 64, 40);

    int gw4 = (n * 4 + 3) / 4;
    int gw1 = (n + 3) / 4;

    // ---- branch 0 ----
    gemm_split(xhi, xlo, W00h, W00l, feat, n, 256, 256, stream);
    k_attn<4, 64><<<gw4, 256, 0, stream>>>(feat, a00l, a00r, el, er, n);
    k_agg4<1, 1><<<gw1, 256, 0, stream>>>(rowptr, csr, el, er, feat, hhi, hlo, nullptr, n);

    gemm_split(hhi, hlo, W01h, W01l, feat, n, 64, 256, stream);
    k_attn<1, 64><<<gw1, 256, 0, stream>>>(feat, a01l, a01r, el, er, n);
    k_agg1<64, 1, 1><<<gw1, 256, 0, stream>>>(rowptr, csr, el, er, feat, hhi, hlo, nullptr, n);

    gemm_split(hhi, hlo, W0fh, W0fl, feat, n, C, 64, stream);
    k_attn<1, 40><<<gw1, 256, 0, stream>>>(feat, a0fl, a0fr, el, er, n);
    k_agg1<40, 0, 0><<<gw1, 256, 0, stream>>>(rowptr, csr, el, er, feat, nullptr, nullptr, out, n);

    // ---- branch 1 ----
    gemm_split(xhi, xlo, W10h, W10l, feat, n, 256, 256, stream);
    k_attn<4, 64><<<gw4, 256, 0, stream>>>(feat, a10l, a10r, el, er, n);
    k_agg4<1, 1><<<gw1, 256, 0, stream>>>(rowptr, csr, el, er, feat, hhi, hlo, nullptr, n);

    gemm_split(hhi, hlo, W1fh, W1fl, feat, n, 64, 256, stream);
    k_attn<1, 64><<<gw1, 256, 0, stream>>>(feat, a1fl, a1fr, el, er, n);
    k_agg1<64, 0, 1><<<gw1, 256, 0, stream>>>(rowptr, csr, el, er, feat, hhi, hlo, nullptr, n);

    gemm_split(hhi, hlo, W1oh, W1ol, feat, n, C, 64, stream);
    k_attn<1, 40><<<gw1, 256, 0, stream>>>(feat, a1ol, a1or, el, er, n);
    k_agg1<40, 1, 0><<<gw1, 256, 0, stream>>>(rowptr, csr, el, er, feat, nullptr, nullptr,
                                              out + (size_t)n * C, n);
}

// Round 4
// 693.721 us; speedup vs baseline: 1.0657x; 1.0657x over previous
//
#include <hip/hip_runtime.h>
#include <math.h>

typedef __attribute__((ext_vector_type(8))) short bf16x8;
typedef __attribute__((ext_vector_type(4))) float f32x4;
typedef __attribute__((ext_vector_type(4))) _Float16 f16x4;

// f32 += f16(lo/hi half of packed dword) * f32  -- exact, single VOP3P instr
#define FMAMIX_LO(acc, pk, s) \
    asm("v_fma_mix_f32 %0, %1, %2, %0 op_sel:[0,0,0] op_sel_hi:[1,0,0]" \
        : "+v"(acc) : "v"(pk), "v"(s))
#define FMAMIX_HI(acc, pk, s) \
    asm("v_fma_mix_f32 %0, %1, %2, %0 op_sel:[1,0,0] op_sel_hi:[1,0,0]" \
        : "+v"(acc) : "v"(pk), "v"(s))

__device__ __forceinline__ unsigned short f2bf(float f) {
    unsigned int u = __float_as_uint(f);
    unsigned int r = (u + 0x7FFF + ((u >> 16) & 1)) >> 16;  // RNE
    return (unsigned short)r;
}
__device__ __forceinline__ float bf2f(unsigned short h) {
    return __uint_as_float((unsigned int)h << 16);
}
__device__ __forceinline__ void split_bf(float x, unsigned short& hi, unsigned short& lo) {
    hi = f2bf(x);
    lo = f2bf(x - bf2f(hi));
}

// ---------------- CSR build ----------------

__global__ void k_hist(const int* __restrict__ dst, int* __restrict__ deg, int e) {
    int t = blockIdx.x * 256 + threadIdx.x;
    if (t < e) atomicAdd(&deg[dst[t]], 1);
}

__global__ void k_scan1(const int* __restrict__ deg, int* __restrict__ tmp,
                        int* __restrict__ bsum, int n) {
    __shared__ int s[1024];
    int t = threadIdx.x;
    int g = blockIdx.x * 1024 + t;
    int v = (g < n) ? deg[g] : 0;
    s[t] = v;
    __syncthreads();
    for (int off = 1; off < 1024; off <<= 1) {
        int u = (t >= off) ? s[t - off] : 0;
        __syncthreads();
        s[t] += u;
        __syncthreads();
    }
    if (g < n) tmp[g] = s[t];
    if (t == 1023) bsum[blockIdx.x] = s[t];
}

__global__ void k_scan2(int* bsum, int nb) {
    int acc = 0;
    for (int b = 0; b < nb; ++b) { int v = bsum[b]; bsum[b] = acc; acc += v; }
}

__global__ void k_scan3(const int* __restrict__ deg, const int* __restrict__ tmp,
                        const int* __restrict__ bsum, int* __restrict__ rowptr,
                        int* __restrict__ cursor, int n) {
    int g = blockIdx.x * 256 + threadIdx.x;
    if (g < n) {
        int incl = tmp[g] + bsum[g >> 10];
        rowptr[g + 1] = incl;
        cursor[g] = incl - deg[g];
        if (g == 0) rowptr[0] = 0;
    }
}

__global__ void k_scatter(const int* __restrict__ src, const int* __restrict__ dst,
                          int* __restrict__ cursor, int* __restrict__ csr, int e) {
    int t = blockIdx.x * 256 + threadIdx.x;
    if (t < e) {
        int d = dst[t];
        int pos = atomicAdd(&cursor[d], 1);
        csr[pos] = src[t];
    }
}

// ---------------- casts (split hi/lo) ----------------

__global__ void k_castx(const float* __restrict__ x, unsigned short* __restrict__ xhi,
                        unsigned short* __restrict__ xlo, int nvec) {
    int t = blockIdx.x * 256 + threadIdx.x;
    if (t < nvec) {
        float4 v = ((const float4*)x)[t];
        ushort4 h, l;
        split_bf(v.x, h.x, l.x);
        split_bf(v.y, h.y, l.y);
        split_bf(v.z, h.z, l.z);
        split_bf(v.w, h.w, l.w);
        ((ushort4*)xhi)[t] = h;
        ((ushort4*)xlo)[t] = l;
    }
}

__global__ void k_castw(const float* __restrict__ W, unsigned short* __restrict__ Whi,
                        unsigned short* __restrict__ Wlo, int K, int N) {
    int t = blockIdx.x * 256 + threadIdx.x;
    if (t < K * N) {
        int k = t / N, n = t - k * N;
        unsigned short h, l;
        split_bf(W[t], h, l);
        Whi[n * K + k] = h; Wlo[n * K + k] = l;
    }
}

// ------- split-bf16 MFMA GEMM (NT): C = A @ Bt^T, ~fp32 accuracy ----------
// Output written as fp16 with row stride ldc (lets two GEMMs interleave
// their outputs into one combined feature buffer).

#define LDP 40

// 64x64-tile kernel (small N: 64, 40)
__global__ __launch_bounds__(256) void k_gemm_split(const unsigned short* __restrict__ Ahi,
                                                    const unsigned short* __restrict__ Alo,
                                                    const unsigned short* __restrict__ Bhi,
                                                    const unsigned short* __restrict__ Blo,
                                                    _Float16* __restrict__ C,
                                                    int M, int Ncol, int K, int ldc) {
    int bx = blockIdx.x, by = blockIdx.y;
    __shared__ unsigned short Ash[64 * LDP];
    __shared__ unsigned short Asl[64 * LDP];
    __shared__ unsigned short Bsh[64 * LDP];
    __shared__ unsigned short Bsl[64 * LDP];
    int t = threadIdx.x;
    int w = t >> 6, lane = t & 63;
    int lrow = lane & 15, kgrp = (lane >> 4) * 8;
    int row0 = bx * 64, col0 = by * 64;
    int trow = t >> 2, tcol = (t & 3) * 8;

    f32x4 acc[4] = {{0.f, 0.f, 0.f, 0.f}, {0.f, 0.f, 0.f, 0.f},
                    {0.f, 0.f, 0.f, 0.f}, {0.f, 0.f, 0.f, 0.f}};

    for (int k0 = 0; k0 < K; k0 += 32) {
        uint4 ah = {0u,0u,0u,0u}, al = {0u,0u,0u,0u};
        uint4 bh = {0u,0u,0u,0u}, bl = {0u,0u,0u,0u};
        int gr = row0 + trow;
        if (gr < M) {
            ah = *(const uint4*)(Ahi + (size_t)gr * K + k0 + tcol);
            al = *(const uint4*)(Alo + (size_t)gr * K + k0 + tcol);
        }
        int gc = col0 + trow;
        if (gc < Ncol) {
            bh = *(const uint4*)(Bhi + (size_t)gc * K + k0 + tcol);
            bl = *(const uint4*)(Blo + (size_t)gc * K + k0 + tcol);
        }
        __syncthreads();
        *(uint4*)&Ash[trow * LDP + tcol] = ah;
        *(uint4*)&Asl[trow * LDP + tcol] = al;
        *(uint4*)&Bsh[trow * LDP + tcol] = bh;
        *(uint4*)&Bsl[trow * LDP + tcol] = bl;
        __syncthreads();
        bf16x8 vbh = *(const bf16x8*)&Bsh[(w * 16 + lrow) * LDP + kgrp];
        bf16x8 vbl = *(const bf16x8*)&Bsl[(w * 16 + lrow) * LDP + kgrp];
        #pragma unroll
        for (int mt = 0; mt < 4; ++mt) {
            bf16x8 vah = *(const bf16x8*)&Ash[(mt * 16 + lrow) * LDP + kgrp];
            bf16x8 val = *(const bf16x8*)&Asl[(mt * 16 + lrow) * LDP + kgrp];
            acc[mt] = __builtin_amdgcn_mfma_f32_16x16x32_bf16(vah, vbh, acc[mt], 0, 0, 0);
            acc[mt] = __builtin_amdgcn_mfma_f32_16x16x32_bf16(val, vbh, acc[mt], 0, 0, 0);
            acc[mt] = __builtin_amdgcn_mfma_f32_16x16x32_bf16(vah, vbl, acc[mt], 0, 0, 0);
        }
    }

    int ocol = col0 + w * 16 + lrow;
    if (ocol < Ncol) {
        int orow = (lane >> 4) * 4;
        #pragma unroll
        for (int mt = 0; mt < 4; ++mt) {
            #pragma unroll
            for (int r = 0; r < 4; ++r) {
                int m = row0 + mt * 16 + orow + r;
                if (m < M) C[(size_t)m * ldc + ocol] = (_Float16)acc[mt][r];
            }
        }
    }
}

// 128x128-tile kernel for Ncol==256. Bijective m204 XCD-chunk swizzle.
__global__ __launch_bounds__(256) void k_gemm128(const unsigned short* __restrict__ Ahi,
                                                 const unsigned short* __restrict__ Alo,
                                                 const unsigned short* __restrict__ Bhi,
                                                 const unsigned short* __restrict__ Blo,
                                                 _Float16* __restrict__ C,
                                                 int M, int Ncol, int K, int ldc) {
    int Mb = (M + 127) >> 7;
    int nwg = Mb * 2;
    int v = blockIdx.x;
    int q = nwg >> 3, r = nwg & 7;
    int xcd = v & 7, idx = v >> 3;
    int wg = (xcd < r ? xcd * (q + 1) : r * (q + 1) + (xcd - r) * q) + idx;
    int bx = wg >> 1, by = wg & 1;
    int row0 = bx * 128, col0 = by * 128;

    __shared__ unsigned short Ash[128 * LDP];
    __shared__ unsigned short Asl[128 * LDP];
    __shared__ unsigned short Bsh[128 * LDP];
    __shared__ unsigned short Bsl[128 * LDP];

    int t = threadIdx.x;
    int w = t >> 6, lane = t & 63;
    int wr = w >> 1, wc = w & 1;
    int lrow = lane & 15, kgrp = (lane >> 4) * 8;
    int trow = t >> 1, tcol = (t & 1) * 16;

    f32x4 acc[4][4];
    #pragma unroll
    for (int mt = 0; mt < 4; ++mt)
        #pragma unroll
        for (int nt = 0; nt < 4; ++nt)
            acc[mt][nt] = (f32x4){0.f, 0.f, 0.f, 0.f};

    for (int k0 = 0; k0 < K; k0 += 32) {
        uint4 a0 = {0u,0u,0u,0u}, a1 = {0u,0u,0u,0u};
        uint4 l0 = {0u,0u,0u,0u}, l1 = {0u,0u,0u,0u};
        uint4 b0 = {0u,0u,0u,0u}, b1 = {0u,0u,0u,0u};
        uint4 m0 = {0u,0u,0u,0u}, m1 = {0u,0u,0u,0u};
        int gr = row0 + trow;
        if (gr < M) {
            const unsigned short* pa = Ahi + (size_t)gr * K + k0 + tcol;
            const unsigned short* pl = Alo + (size_t)gr * K + k0 + tcol;
            a0 = *(const uint4*)pa;       a1 = *(const uint4*)(pa + 8);
            l0 = *(const uint4*)pl;       l1 = *(const uint4*)(pl + 8);
        }
        int gc = col0 + trow;
        if (gc < Ncol) {
            const unsigned short* pb = Bhi + (size_t)gc * K + k0 + tcol;
            const unsigned short* pm = Blo + (size_t)gc * K + k0 + tcol;
            b0 = *(const uint4*)pb;       b1 = *(const uint4*)(pb + 8);
            m0 = *(const uint4*)pm;       m1 = *(const uint4*)(pm + 8);
        }
        __syncthreads();
        *(uint4*)&Ash[trow * LDP + tcol]     = a0;
        *(uint4*)&Ash[trow * LDP + tcol + 8] = a1;
        *(uint4*)&Asl[trow * LDP + tcol]     = l0;
        *(uint4*)&Asl[trow * LDP + tcol + 8] = l1;
        *(uint4*)&Bsh[trow * LDP + tcol]     = b0;
        *(uint4*)&Bsh[trow * LDP + tcol + 8] = b1;
        *(uint4*)&Bsl[trow * LDP + tcol]     = m0;
        *(uint4*)&Bsl[trow * LDP + tcol + 8] = m1;
        __syncthreads();

        bf16x8 vbh[4], vbl[4];
        #pragma unroll
        for (int nt = 0; nt < 4; ++nt) {
            vbh[nt] = *(const bf16x8*)&Bsh[(wc * 64 + nt * 16 + lrow) * LDP + kgrp];
            vbl[nt] = *(const bf16x8*)&Bsl[(wc * 64 + nt * 16 + lrow) * LDP + kgrp];
        }
        #pragma unroll
        for (int mt = 0; mt < 4; ++mt) {
            bf16x8 vah = *(const bf16x8*)&Ash[(wr * 64 + mt * 16 + lrow) * LDP + kgrp];
            bf16x8 val = *(const bf16x8*)&Asl[(wr * 64 + mt * 16 + lrow) * LDP + kgrp];
            #pragma unroll
            for (int nt = 0; nt < 4; ++nt) {
                acc[mt][nt] = __builtin_amdgcn_mfma_f32_16x16x32_bf16(vah, vbh[nt], acc[mt][nt], 0, 0, 0);
                acc[mt][nt] = __builtin_amdgcn_mfma_f32_16x16x32_bf16(val, vbh[nt], acc[mt][nt], 0, 0, 0);
                acc[mt][nt] = __builtin_amdgcn_mfma_f32_16x16x32_bf16(vah, vbl[nt], acc[mt][nt], 0, 0, 0);
            }
        }
    }

    int orow = (lane >> 4) * 4;
    #pragma unroll
    for (int mt = 0; mt < 4; ++mt) {
        #pragma unroll
        for (int nt = 0; nt < 4; ++nt) {
            int oc = col0 + wc * 64 + nt * 16 + lrow;
            #pragma unroll
            for (int rr = 0; rr < 4; ++rr) {
                int m = row0 + wr * 64 + mt * 16 + orow + rr;
                if (m < M) C[(size_t)m * ldc + oc] = (_Float16)acc[mt][nt][rr];
            }
        }
    }
}

static inline void gemm_split(const unsigned short* Ah, const unsigned short* Al,
                              const unsigned short* Bh, const unsigned short* Bl,
                              _Float16* C, int M, int Ncol, int K, int ldc, hipStream_t st) {
    if (Ncol == 256) {
        int Mb = (M + 127) / 128;
        k_gemm128<<<Mb * 2, 256, 0, st>>>(Ah, Al, Bh, Bl, C, M, Ncol, K, ldc);
    } else {
        int Mb = (M + 63) / 64, Nb = (Ncol + 63) / 64;
        k_gemm_split<<<dim3(Mb, Nb), 256, 0, st>>>(Ah, Al, Bh, Bl, C, M, Ncol, K, ldc);
    }
}

// ---------------- attention scores ----------------

// generic (H=1 layers): feat row stride = D
template <int H, int D>
__global__ __launch_bounds__(256) void k_attn(const _Float16* __restrict__ feat,
                                              const float* __restrict__ al,
                                              const float* __restrict__ ar,
                                              float* __restrict__ el,
                                              float* __restrict__ er, int n) {
    int gw = blockIdx.x * 4 + (threadIdx.x >> 6);
    int lane = threadIdx.x & 63;
    int i = gw / H, h = gw % H;
    if (i >= n) return;
    float f = (lane < D) ? (float)feat[i * (H * D) + h * D + lane] : 0.f;
    float wl = (lane < D) ? al[h * D + lane] : 0.f;
    float wr = (lane < D) ? ar[h * D + lane] : 0.f;
    float pl = f * wl, pr = f * wr;
    #pragma unroll
    for (int off = 32; off; off >>= 1) {
        pl += __shfl_xor(pl, off);
        pr += __shfl_xor(pr, off);
    }
    if (lane == 0) {
        el[i * H + h] = pl;
        er[i * H + h] = pr;
    }
}

// fused layer-0 scores for both branches: featC rows are [b0:256ch | b1:256ch],
// el8/er8 layout [i][h][b] (8 floats per node -> float2 per (h) gives both b)
__global__ __launch_bounds__(256) void k_attn4x2(const _Float16* __restrict__ featC,
                                                 const float* __restrict__ a0l,
                                                 const float* __restrict__ a0r,
                                                 const float* __restrict__ a1l,
                                                 const float* __restrict__ a1r,
                                                 float* __restrict__ el8,
                                                 float* __restrict__ er8, int n) {
    int gw = blockIdx.x * 4 + (threadIdx.x >> 6);
    int lane = threadIdx.x & 63;
    int i = gw >> 3;
    if (i >= n) return;
    int rem = gw & 7;
    int b = rem >> 2, h = rem & 3;
    const float* al = b ? a1l : a0l;
    const float* ar = b ? a1r : a0r;
    float f = (float)featC[(size_t)i * 512 + b * 256 + h * 64 + lane];
    float pl = f * al[h * 64 + lane];
    float pr = f * ar[h * 64 + lane];
    #pragma unroll
    for (int off = 32; off; off >>= 1) {
        pl += __shfl_xor(pl, off);
        pr += __shfl_xor(pr, off);
    }
    if (lane == 0) {
        el8[i * 8 + h * 2 + b] = pl;
        er8[i * 8 + h * 2 + b] = pr;
    }
}

__device__ __forceinline__ float lrelu(float v) { return v > 0.f ? v : 0.2f * v; }

// -------- FUSED H=4 aggregation for BOTH branches: ONE WAVE per dst -------
// featC row = 1KB (two branches interleaved) -> per edge ONE uint4/lane
// gather covering both branches (longer random bursts, one csr/softmax pass).
// Lane roles: exp stage (eidx=lane>>2, h=lane&3, both b per lane);
// FMA stage: b=lane>>5, hh=(lane>>3)&3, 8 channels per lane.
#define A42_ISSUE(J) uint4 q##J = *(const uint4*)(featLane + ((size_t)(unsigned)__shfl(s, (J) << 2) << 10))
#define A42_CONS(J, X) \
    FMAMIX_LO(f0, q##J.x, X); FMAMIX_HI(f1, q##J.x, X); \
    FMAMIX_LO(f2, q##J.y, X); FMAMIX_HI(f3, q##J.y, X); \
    FMAMIX_LO(f4, q##J.z, X); FMAMIX_HI(f5, q##J.z, X); \
    FMAMIX_LO(f6, q##J.w, X); FMAMIX_HI(f7, q##J.w, X)

__global__ __launch_bounds__(256) void k_agg4x2(const int* __restrict__ rowptr,
                                                const int* __restrict__ csr,
                                                const float* __restrict__ el8,
                                                const float* __restrict__ er8,
                                                const _Float16* __restrict__ featC,
                                                unsigned short* __restrict__ b0hi,
                                                unsigned short* __restrict__ b0lo,
                                                unsigned short* __restrict__ b1hi,
                                                unsigned short* __restrict__ b1lo,
                                                int n) {
    __shared__ float s_ex[4][128];  // [wave][b*64 + h*16 + eidx]
    int w = threadIdx.x >> 6;
    int lane = threadIdx.x & 63;
    int i = blockIdx.x * 4 + w;
    if (i >= n) return;
    int s0 = rowptr[i], s1 = rowptr[i + 1];
    int deg = s1 - s0;
    int eidx = lane >> 2, h = lane & 3;     // exp-stage role
    int b = lane >> 5, hh = (lane >> 3) & 3; // FMA/output-stage role
    float2 erp = *(const float2*)&er8[i * 8 + h * 2];  // (b0, b1) for head h
    const char* featLane = (const char*)featC + (lane << 4);

    float den0 = 0.f, den1 = 0.f;
    float m0 = -INFINITY, m1 = -INFINITY;
    float f0 = 0.f, f1 = 0.f, f2 = 0.f, f3 = 0.f;
    float f4 = 0.f, f5 = 0.f, f6 = 0.f, f7 = 0.f;

    int e0 = s0 + eidx;
    int s = (e0 < s1) ? csr[e0] : 0;
    for (int c = s0; c < s1; c += 16) {
        bool val = (c + eidx < s1);
        // critical-chain load first (softmax depends on it)
        float2 elp = *(const float2*)&el8[(s << 3) + h * 2];
        // 16 edge gathers (1KB row each) into registers
        A42_ISSUE(0);  A42_ISSUE(1);  A42_ISSUE(2);  A42_ISSUE(3);
        A42_ISSUE(4);  A42_ISSUE(5);  A42_ISSUE(6);  A42_ISSUE(7);
        A42_ISSUE(8);  A42_ISSUE(9);  A42_ISSUE(10); A42_ISSUE(11);
        A42_ISSUE(12); A42_ISSUE(13); A42_ISSUE(14); A42_ISSUE(15);
        // prefetch next chunk's csr
        int en = c + 16 + eidx;
        int sn = (en < s1) ? csr[en] : 0;
        // twin online-softmax chains (overlap the gathers)
        float v0 = val ? lrelu(elp.x + erp.x) : -INFINITY;
        float v1 = val ? lrelu(elp.y + erp.y) : -INFINITY;
        float cm0 = v0, cm1 = v1;
        #pragma unroll
        for (int off = 4; off < 64; off <<= 1) {
            cm0 = fmaxf(cm0, __shfl_xor(cm0, off));
            cm1 = fmaxf(cm1, __shfl_xor(cm1, off));
        }
        float mn0 = fmaxf(m0, cm0), mn1 = fmaxf(m1, cm1);
        float sc0 = __expf(m0 - mn0), sc1 = __expf(m1 - mn1);
        m0 = mn0; m1 = mn1;
        float ex0 = val ? __expf(v0 - mn0) : 0.f;
        float ex1 = val ? __expf(v1 - mn1) : 0.f;
        den0 = den0 * sc0 + ex0;
        den1 = den1 * sc1 + ex1;
        s_ex[w][(h << 4) + eidx] = ex0;
        s_ex[w][64 + (h << 4) + eidx] = ex1;
        float sb0 = __shfl(sc0, hh), sb1 = __shfl(sc1, hh);
        float scl = (lane < 32) ? sb0 : sb1;
        f0 *= scl; f1 *= scl; f2 *= scl; f3 *= scl;
        f4 *= scl; f5 *= scl; f6 *= scl; f7 *= scl;
        // consume
        const float* exrow = &s_ex[w][(b << 6) + (hh << 4)];
        float4 x0 = *(const float4*)&exrow[0];
        float4 x1 = *(const float4*)&exrow[4];
        float4 x2 = *(const float4*)&exrow[8];
        float4 x3 = *(const float4*)&exrow[12];
        A42_CONS(0, x0.x);  A42_CONS(1, x0.y);  A42_CONS(2, x0.z);  A42_CONS(3, x0.w);
        A42_CONS(4, x1.x);  A42_CONS(5, x1.y);  A42_CONS(6, x1.z);  A42_CONS(7, x1.w);
        A42_CONS(8, x2.x);  A42_CONS(9, x2.y);  A42_CONS(10, x2.z); A42_CONS(11, x2.w);
        A42_CONS(12, x3.x); A42_CONS(13, x3.y); A42_CONS(14, x3.z); A42_CONS(15, x3.w);
        s = sn;
    }

    #pragma unroll
    for (int off = 4; off < 64; off <<= 1) {
        den0 += __shfl_xor(den0, off);
        den1 += __shfl_xor(den1, off);
    }
    float db0 = __shfl(den0, hh), db1 = __shfl(den1, hh);
    float d = fmaxf((lane < 32) ? db0 : db1, 1e-9f);

    float o0 = (deg > 0) ? f0 / d : 0.f;
    float o1 = (deg > 0) ? f1 / d : 0.f;
    float o2 = (deg > 0) ? f2 / d : 0.f;
    float o3 = (deg > 0) ? f3 / d : 0.f;
    float o4 = (deg > 0) ? f4 / d : 0.f;
    float o5 = (deg > 0) ? f5 / d : 0.f;
    float o6 = (deg > 0) ? f6 / d : 0.f;
    float o7 = (deg > 0) ? f7 / d : 0.f;
    // elu (both branches' layer-0 use elu)
    o0 = o0 > 0.f ? o0 : (__expf(o0) - 1.f);
    o1 = o1 > 0.f ? o1 : (__expf(o1) - 1.f);
    o2 = o2 > 0.f ? o2 : (__expf(o2) - 1.f);
    o3 = o3 > 0.f ? o3 : (__expf(o3) - 1.f);
    o4 = o4 > 0.f ? o4 : (__expf(o4) - 1.f);
    o5 = o5 > 0.f ? o5 : (__expf(o5) - 1.f);
    o6 = o6 > 0.f ? o6 : (__expf(o6) - 1.f);
    o7 = o7 > 0.f ? o7 : (__expf(o7) - 1.f);

    ushort4 vhA, vlA, vhB, vlB;
    split_bf(o0, vhA.x, vlA.x);
    split_bf(o1, vhA.y, vlA.y);
    split_bf(o2, vhA.z, vlA.z);
    split_bf(o3, vhA.w, vlA.w);
    split_bf(o4, vhB.x, vlB.x);
    split_bf(o5, vhB.y, vlB.y);
    split_bf(o6, vhB.z, vlB.z);
    split_bf(o7, vhB.w, vlB.w);
    size_t base = (size_t)i * 256 + ((lane & 31) << 3);
    if (lane < 32) {
        *(ushort4*)&b0hi[base] = vhA;  *(ushort4*)&b0hi[base + 4] = vhB;
        *(ushort4*)&b0lo[base] = vlA;  *(ushort4*)&b0lo[base + 4] = vlB;
    } else {
        *(ushort4*)&b1hi[base] = vhA;  *(ushort4*)&b1hi[base + 4] = vhB;
        *(ushort4*)&b1lo[base] = vlA;  *(ushort4*)&b1lo[base + 4] = vlB;
    }
}

// ---------------- H=1 aggregation (R2 form: LDS offsets + fma_mix) --------

template <int D, int ACT, int SPLITOUT>
__global__ __launch_bounds__(256) void k_agg1(const int* __restrict__ rowptr,
                                              const int* __restrict__ csr,
                                              const float* __restrict__ el,
                                              const float* __restrict__ er,
                                              const _Float16* __restrict__ feat,
                                              unsigned short* __restrict__ ohi,
                                              unsigned short* __restrict__ olo,
                                              float* __restrict__ ofp, int n) {
    __shared__ int   s_off[4][64];
    __shared__ float s_ex[4][64];
    int w = threadIdx.x >> 6;
    int i = blockIdx.x * 4 + w;
    int lane = threadIdx.x & 63;
    if (i >= n) return;
    int s0 = rowptr[i], s1 = rowptr[i + 1];
    int deg = s1 - s0;
    float eri = er[i];
    bool act = lane < D;
    const char* featLane = (const char*)feat + lane * 2;

    float den = 0.f, acc = 0.f;

    auto fma_chunk = [&](int cnt) {
        int j = 0;
        for (; j + 4 <= cnt; j += 4) {
            int4   oj = *(const int4*)&s_off[w][j];
            float4 xj = *(const float4*)&s_ex[w][j];
            unsigned int u0 = act ? (unsigned int)*(const unsigned short*)(featLane + oj.x) : 0u;
            unsigned int u1 = act ? (unsigned int)*(const unsigned short*)(featLane + oj.y) : 0u;
            unsigned int u2 = act ? (unsigned int)*(const unsigned short*)(featLane + oj.z) : 0u;
            unsigned int u3 = act ? (unsigned int)*(const unsigned short*)(featLane + oj.w) : 0u;
            FMAMIX_LO(acc, u0, xj.x);
            FMAMIX_LO(acc, u1, xj.y);
            FMAMIX_LO(acc, u2, xj.z);
            FMAMIX_LO(acc, u3, xj.w);
        }
        for (; j < cnt; ++j) {
            unsigned int u0 = act ? (unsigned int)*(const unsigned short*)(featLane + s_off[w][j]) : 0u;
            float x = s_ex[w][j];
            FMAMIX_LO(acc, u0, x);
        }
    };

    if (deg <= 64) {
        int e = s0 + lane;
        int s = 0;
        float v = -INFINITY;
        if (e < s1) {
            s = csr[e];
            v = lrelu(el[s] + eri);
        }
        float m = v;
        #pragma unroll
        for (int off = 32; off; off >>= 1) m = fmaxf(m, __shfl_xor(m, off));
        float ex = (e < s1) ? __expf(v - m) : 0.f;
        den = ex;
        s_off[w][lane] = s * (D * 2);
        s_ex[w][lane] = ex;
        fma_chunk(deg);
    } else {
        float m = -INFINITY;
        for (int c = s0; c < s1; c += 64) {
            int e = c + lane;
            int s = 0;
            float ex = 0.f;
            float v = -INFINITY;
            if (e < s1) {
                s = csr[e];
                v = lrelu(el[s] + eri);
            }
            float cm = v;
            #pragma unroll
            for (int off = 32; off; off >>= 1) cm = fmaxf(cm, __shfl_xor(cm, off));
            float mn = fmaxf(m, cm);
            float scale = __expf(m - mn);
            m = mn;
            ex = (e < s1) ? __expf(v - mn) : 0.f;
            den = den * scale + ex;
            acc *= scale;
            s_off[w][lane] = s * (D * 2);
            s_ex[w][lane] = ex;
            fma_chunk(min(64, s1 - c));
        }
    }
    #pragma unroll
    for (int off = 32; off; off >>= 1) den += __shfl_xor(den, off);

    float o = (deg > 0) ? acc / fmaxf(den, 1e-9f) : 0.f;
    if (ACT == 1) o = o > 0.f ? o : (__expf(o) - 1.f);
    if (act) {
        if (SPLITOUT) {
            unsigned short oh, ol;
            split_bf(o, oh, ol);
            ohi[(size_t)i * D + lane] = oh;
            olo[(size_t)i * D + lane] = ol;
        } else {
            ofp[(size_t)i * D + lane] = o;
        }
    }
}

// ---------------- launch ----------------

extern "C" void kernel_launch(void* const* d_in, const int* in_sizes, int n_in,
                              void* d_out, int out_size, void* d_ws, size_t ws_size,
                              hipStream_t stream) {
    const float* x    = (const float*)d_in[0];
    const int*   src  = (const int*)d_in[1];
    const int*   dst  = (const int*)d_in[2];
    const float* W00  = (const float*)d_in[3];
    const float* a00l = (const float*)d_in[4];
    const float* a00r = (const float*)d_in[5];
    const float* W01  = (const float*)d_in[6];
    const float* a01l = (const float*)d_in[7];
    const float* a01r = (const float*)d_in[8];
    const float* W0f  = (const float*)d_in[9];
    const float* a0fl = (const float*)d_in[10];
    const float* a0fr = (const float*)d_in[11];
    const float* W10  = (const float*)d_in[12];
    const float* a10l = (const float*)d_in[13];
    const float* a10r = (const float*)d_in[14];
    const float* W1f  = (const float*)d_in[15];
    const float* a1fl = (const float*)d_in[16];
    const float* a1fr = (const float*)d_in[17];
    const float* W1o  = (const float*)d_in[18];
    const float* a1ol = (const float*)d_in[19];
    const float* a1or = (const float*)d_in[20];
    float* out = (float*)d_out;

    const int n = in_sizes[0] / 256;  // 50000
    const int e = in_sizes[1];        // 800000
    const int C = 40;

    char* p = (char*)d_ws;
    auto alloc = [&](size_t bytes) -> void* {
        void* r = (void*)p;
        p += (bytes + 255) & ~(size_t)255;
        return r;
    };
    int*   deg     = (int*)alloc((size_t)n * 4);
    int*   tmp     = (int*)alloc((size_t)n * 4);
    int*   bsum    = (int*)alloc(64 * 4);
    int*   rowptr  = (int*)alloc((size_t)(n + 1) * 4);
    int*   cursor  = (int*)alloc((size_t)n * 4);
    int*   csr     = (int*)alloc((size_t)e * 4);
    float* el8     = (float*)alloc((size_t)n * 8 * 4);
    float* er8     = (float*)alloc((size_t)n * 8 * 4);
    _Float16* featC = (_Float16*)alloc((size_t)n * 512 * 2 + 256);  // 1KB rows (L0) / reused ld=64,40 later
    unsigned short* xhi = (unsigned short*)alloc((size_t)n * 256 * 2);  // x split; reused as branch1 h
    unsigned short* xlo = (unsigned short*)alloc((size_t)n * 256 * 2);
    unsigned short* hhi = (unsigned short*)alloc((size_t)n * 256 * 2);
    unsigned short* hlo = (unsigned short*)alloc((size_t)n * 256 * 2);
    unsigned short* W00h = (unsigned short*)alloc(256 * 256 * 2);
    unsigned short* W00l = (unsigned short*)alloc(256 * 256 * 2);
    unsigned short* W01h = (unsigned short*)alloc(256 * 64 * 2);
    unsigned short* W01l = (unsigned short*)alloc(256 * 64 * 2);
    unsigned short* W0fh = (unsigned short*)alloc(64 * 40 * 2);
    unsigned short* W0fl = (unsigned short*)alloc(64 * 40 * 2);
    unsigned short* W10h = (unsigned short*)alloc(256 * 256 * 2);
    unsigned short* W10l = (unsigned short*)alloc(256 * 256 * 2);
    unsigned short* W1fh = (unsigned short*)alloc(256 * 64 * 2);
    unsigned short* W1fl = (unsigned short*)alloc(256 * 64 * 2);
    unsigned short* W1oh = (unsigned short*)alloc(64 * 40 * 2);
    unsigned short* W1ol = (unsigned short*)alloc(64 * 40 * 2);

    // ---- CSR build ----
    hipMemsetAsync(deg, 0, (size_t)n * 4, stream);
    k_hist<<<(e + 255) / 256, 256, 0, stream>>>(dst, deg, e);
    int nb = (n + 1023) / 1024;
    k_scan1<<<nb, 1024, 0, stream>>>(deg, tmp, bsum, n);
    k_scan2<<<1, 1, 0, stream>>>(bsum, nb);
    k_scan3<<<(n + 255) / 256, 256, 0, stream>>>(deg, tmp, bsum, rowptr, cursor, n);
    k_scatter<<<(e + 255) / 256, 256, 0, stream>>>(src, dst, cursor, csr, e);

    // ---- casts ----
    int nel = n * 256;
    k_castx<<<(nel / 4 + 255) / 256, 256, 0, stream>>>(x, xhi, xlo, nel / 4);
    k_castw<<<(256 * 256 + 255) / 256, 256, 0, stream>>>(W00, W00h, W00l, 256, 256);
    k_castw<<<(256 * 64 + 255) / 256, 256, 0, stream>>>(W01, W01h, W01l, 256, 64);
    k_castw<<<(64 * 40 + 255) / 256, 256, 0, stream>>>(W0f, W0fh, W0fl, 64, 40);
    k_castw<<<(256 * 256 + 255) / 256, 256, 0, stream>>>(W10, W10h, W10l, 256, 256);
    k_castw<<<(256 * 64 + 255) / 256, 256, 0, stream>>>(W1f, W1fh, W1fl, 256, 64);
    k_castw<<<(64 * 40 + 255) / 256, 256, 0, stream>>>(W1o, W1oh, W1ol, 64, 40);

    int gw1 = (n + 3) / 4;

    // ---- fused layer 0 (both branches) ----
    gemm_split(xhi, xlo, W00h, W00l, featC,       n, 256, 256, 512, stream);
    gemm_split(xhi, xlo, W10h, W10l, featC + 256, n, 256, 256, 512, stream);
    k_attn4x2<<<(n * 8 + 3) / 4, 256, 0, stream>>>(featC, a00l, a00r, a10l, a10r, el8, er8, n);
    // writes: branch0 -> hhi/hlo, branch1 -> xhi/xlo (x split dead after L0 GEMMs)
    k_agg4x2<<<gw1, 256, 0, stream>>>(rowptr, csr, el8, er8, featC, hhi, hlo, xhi, xlo, n);

    // ---- branch 0 rest ----
    gemm_split(hhi, hlo, W01h, W01l, featC, n, 64, 256, 64, stream);
    k_attn<1, 64><<<gw1, 256, 0, stream>>>(featC, a01l, a01r, el8, er8, n);
    k_agg1<64, 1, 1><<<gw1, 256, 0, stream>>>(rowptr, csr, el8, er8, featC, hhi, hlo, nullptr, n);

    gemm_split(hhi, hlo, W0fh, W0fl, featC, n, C, 64, C, stream);
    k_attn<1, 40><<<gw1, 256, 0, stream>>>(featC, a0fl, a0fr, el8, er8, n);
    k_agg1<40, 0, 0><<<gw1, 256, 0, stream>>>(rowptr, csr, el8, er8, featC, nullptr, nullptr, out, n);

    // ---- branch 1 rest (h1 split lives in xhi/xlo) ----
    gemm_split(xhi, xlo, W1fh, W1fl, featC, n, 64, 256, 64, stream);
    k_attn<1, 64><<<gw1, 256, 0, stream>>>(featC, a1fl, a1fr, el8, er8, n);
    k_agg1<64, 0, 1><<<gw1, 256, 0, stream>>>(rowptr, csr, el8, er8, featC, hhi, hlo, nullptr, n);

    gemm_split(hhi, hlo, W1oh, W1ol, featC, n, C, 64, C, stream);
    k_attn<1, 40><<<gw1, 256, 0, stream>>>(featC, a1ol, a1or, el8, er8, n);
    k_agg1<40, 1, 0><<<gw1, 256, 0, stream>>>(rowptr, csr, el8, er8, featC, nullptr, nullptr,
                                              out + (size_t)n * C, n);
}

// Round 5
// 646.929 us; speedup vs baseline: 1.1427x; 1.0723x over previous
//
#include <hip/hip_runtime.h>
#include <math.h>

typedef __attribute__((ext_vector_type(8))) short bf16x8;
typedef __attribute__((ext_vector_type(4))) float f32x4;

// f32 += f16(lo/hi half of packed dword) * f32  -- exact, single VOP3P instr
#define FMAMIX_LO(acc, pk, s) \
    asm("v_fma_mix_f32 %0, %1, %2, %0 op_sel:[0,0,0] op_sel_hi:[1,0,0]" \
        : "+v"(acc) : "v"(pk), "v"(s))
#define FMAMIX_HI(acc, pk, s) \
    asm("v_fma_mix_f32 %0, %1, %2, %0 op_sel:[1,0,0] op_sel_hi:[1,0,0]" \
        : "+v"(acc) : "v"(pk), "v"(s))

__device__ __forceinline__ unsigned short f2bf(float f) {
    unsigned int u = __float_as_uint(f);
    unsigned int r = (u + 0x7FFF + ((u >> 16) & 1)) >> 16;  // RNE
    return (unsigned short)r;
}
__device__ __forceinline__ float bf2f(unsigned short h) {
    return __uint_as_float((unsigned int)h << 16);
}
__device__ __forceinline__ void split_bf(float x, unsigned short& hi, unsigned short& lo) {
    hi = f2bf(x);
    lo = f2bf(x - bf2f(hi));
}

// ---------------- CSR build ----------------

__global__ void k_hist(const int* __restrict__ dst, int* __restrict__ deg, int e) {
    int t = blockIdx.x * 256 + threadIdx.x;
    if (t < e) atomicAdd(&deg[dst[t]], 1);
}

__global__ void k_scan1(const int* __restrict__ deg, int* __restrict__ tmp,
                        int* __restrict__ bsum, int n) {
    __shared__ int s[1024];
    int t = threadIdx.x;
    int g = blockIdx.x * 1024 + t;
    int v = (g < n) ? deg[g] : 0;
    s[t] = v;
    __syncthreads();
    for (int off = 1; off < 1024; off <<= 1) {
        int u = (t >= off) ? s[t - off] : 0;
        __syncthreads();
        s[t] += u;
        __syncthreads();
    }
    if (g < n) tmp[g] = s[t];
    if (t == 1023) bsum[blockIdx.x] = s[t];
}

__global__ void k_scan2(int* bsum, int nb) {
    int acc = 0;
    for (int b = 0; b < nb; ++b) { int v = bsum[b]; bsum[b] = acc; acc += v; }
}

__global__ void k_scan3(const int* __restrict__ deg, const int* __restrict__ tmp,
                        const int* __restrict__ bsum, int* __restrict__ rowptr,
                        int* __restrict__ cursor, int n) {
    int g = blockIdx.x * 256 + threadIdx.x;
    if (g < n) {
        int incl = tmp[g] + bsum[g >> 10];
        rowptr[g + 1] = incl;
        cursor[g] = incl - deg[g];
        if (g == 0) rowptr[0] = 0;
    }
}

__global__ void k_scatter(const int* __restrict__ src, const int* __restrict__ dst,
                          int* __restrict__ cursor, int* __restrict__ csr, int e) {
    int t = blockIdx.x * 256 + threadIdx.x;
    if (t < e) {
        int d = dst[t];
        int pos = atomicAdd(&cursor[d], 1);
        csr[pos] = src[t];
    }
}

// ---------------- casts (split hi/lo) ----------------

__global__ void k_castx(const float* __restrict__ x, unsigned short* __restrict__ xhi,
                        unsigned short* __restrict__ xlo, int nvec) {
    int t = blockIdx.x * 256 + threadIdx.x;
    if (t < nvec) {
        float4 v = ((const float4*)x)[t];
        ushort4 h, l;
        split_bf(v.x, h.x, l.x);
        split_bf(v.y, h.y, l.y);
        split_bf(v.z, h.z, l.z);
        split_bf(v.w, h.w, l.w);
        ((ushort4*)xhi)[t] = h;
        ((ushort4*)xlo)[t] = l;
    }
}

__global__ void k_castw(const float* __restrict__ W, unsigned short* __restrict__ Whi,
                        unsigned short* __restrict__ Wlo, int K, int N) {
    int t = blockIdx.x * 256 + threadIdx.x;
    if (t < K * N) {
        int k = t / N, n = t - k * N;
        unsigned short h, l;
        split_bf(W[t], h, l);
        Whi[n * K + k] = h; Wlo[n * K + k] = l;
    }
}

// ------- split-bf16 MFMA GEMM (NT): C = A @ Bt^T, ~fp32 accuracy ----------
// Output written as fp16 with row stride ldc (lets two GEMMs interleave
// their outputs into one combined feature buffer).

#define LDP 40

// 64x64-tile kernel (small N: 64, 40)
__global__ __launch_bounds__(256) void k_gemm_split(const unsigned short* __restrict__ Ahi,
                                                    const unsigned short* __restrict__ Alo,
                                                    const unsigned short* __restrict__ Bhi,
                                                    const unsigned short* __restrict__ Blo,
                                                    _Float16* __restrict__ C,
                                                    int M, int Ncol, int K, int ldc) {
    int bx = blockIdx.x, by = blockIdx.y;
    __shared__ unsigned short Ash[64 * LDP];
    __shared__ unsigned short Asl[64 * LDP];
    __shared__ unsigned short Bsh[64 * LDP];
    __shared__ unsigned short Bsl[64 * LDP];
    int t = threadIdx.x;
    int w = t >> 6, lane = t & 63;
    int lrow = lane & 15, kgrp = (lane >> 4) * 8;
    int row0 = bx * 64, col0 = by * 64;
    int trow = t >> 2, tcol = (t & 3) * 8;

    f32x4 acc[4] = {{0.f, 0.f, 0.f, 0.f}, {0.f, 0.f, 0.f, 0.f},
                    {0.f, 0.f, 0.f, 0.f}, {0.f, 0.f, 0.f, 0.f}};

    for (int k0 = 0; k0 < K; k0 += 32) {
        uint4 ah = {0u,0u,0u,0u}, al = {0u,0u,0u,0u};
        uint4 bh = {0u,0u,0u,0u}, bl = {0u,0u,0u,0u};
        int gr = row0 + trow;
        if (gr < M) {
            ah = *(const uint4*)(Ahi + (size_t)gr * K + k0 + tcol);
            al = *(const uint4*)(Alo + (size_t)gr * K + k0 + tcol);
        }
        int gc = col0 + trow;
        if (gc < Ncol) {
            bh = *(const uint4*)(Bhi + (size_t)gc * K + k0 + tcol);
            bl = *(const uint4*)(Blo + (size_t)gc * K + k0 + tcol);
        }
        __syncthreads();
        *(uint4*)&Ash[trow * LDP + tcol] = ah;
        *(uint4*)&Asl[trow * LDP + tcol] = al;
        *(uint4*)&Bsh[trow * LDP + tcol] = bh;
        *(uint4*)&Bsl[trow * LDP + tcol] = bl;
        __syncthreads();
        bf16x8 vbh = *(const bf16x8*)&Bsh[(w * 16 + lrow) * LDP + kgrp];
        bf16x8 vbl = *(const bf16x8*)&Bsl[(w * 16 + lrow) * LDP + kgrp];
        #pragma unroll
        for (int mt = 0; mt < 4; ++mt) {
            bf16x8 vah = *(const bf16x8*)&Ash[(mt * 16 + lrow) * LDP + kgrp];
            bf16x8 val = *(const bf16x8*)&Asl[(mt * 16 + lrow) * LDP + kgrp];
            acc[mt] = __builtin_amdgcn_mfma_f32_16x16x32_bf16(vah, vbh, acc[mt], 0, 0, 0);
            acc[mt] = __builtin_amdgcn_mfma_f32_16x16x32_bf16(val, vbh, acc[mt], 0, 0, 0);
            acc[mt] = __builtin_amdgcn_mfma_f32_16x16x32_bf16(vah, vbl, acc[mt], 0, 0, 0);
        }
    }

    int ocol = col0 + w * 16 + lrow;
    if (ocol < Ncol) {
        int orow = (lane >> 4) * 4;
        #pragma unroll
        for (int mt = 0; mt < 4; ++mt) {
            #pragma unroll
            for (int r = 0; r < 4; ++r) {
                int m = row0 + mt * 16 + orow + r;
                if (m < M) C[(size_t)m * ldc + ocol] = (_Float16)acc[mt][r];
            }
        }
    }
}

// 128x128-tile kernel for Ncol==256. Bijective m204 XCD-chunk swizzle.
__global__ __launch_bounds__(256) void k_gemm128(const unsigned short* __restrict__ Ahi,
                                                 const unsigned short* __restrict__ Alo,
                                                 const unsigned short* __restrict__ Bhi,
                                                 const unsigned short* __restrict__ Blo,
                                                 _Float16* __restrict__ C,
                                                 int M, int Ncol, int K, int ldc) {
    int Mb = (M + 127) >> 7;
    int nwg = Mb * 2;
    int v = blockIdx.x;
    int q = nwg >> 3, r = nwg & 7;
    int xcd = v & 7, idx = v >> 3;
    int wg = (xcd < r ? xcd * (q + 1) : r * (q + 1) + (xcd - r) * q) + idx;
    int bx = wg >> 1, by = wg & 1;
    int row0 = bx * 128, col0 = by * 128;

    __shared__ unsigned short Ash[128 * LDP];
    __shared__ unsigned short Asl[128 * LDP];
    __shared__ unsigned short Bsh[128 * LDP];
    __shared__ unsigned short Bsl[128 * LDP];

    int t = threadIdx.x;
    int w = t >> 6, lane = t & 63;
    int wr = w >> 1, wc = w & 1;
    int lrow = lane & 15, kgrp = (lane >> 4) * 8;
    int trow = t >> 1, tcol = (t & 1) * 16;

    f32x4 acc[4][4];
    #pragma unroll
    for (int mt = 0; mt < 4; ++mt)
        #pragma unroll
        for (int nt = 0; nt < 4; ++nt)
            acc[mt][nt] = (f32x4){0.f, 0.f, 0.f, 0.f};

    for (int k0 = 0; k0 < K; k0 += 32) {
        uint4 a0 = {0u,0u,0u,0u}, a1 = {0u,0u,0u,0u};
        uint4 l0 = {0u,0u,0u,0u}, l1 = {0u,0u,0u,0u};
        uint4 b0 = {0u,0u,0u,0u}, b1 = {0u,0u,0u,0u};
        uint4 m0 = {0u,0u,0u,0u}, m1 = {0u,0u,0u,0u};
        int gr = row0 + trow;
        if (gr < M) {
            const unsigned short* pa = Ahi + (size_t)gr * K + k0 + tcol;
            const unsigned short* pl = Alo + (size_t)gr * K + k0 + tcol;
            a0 = *(const uint4*)pa;       a1 = *(const uint4*)(pa + 8);
            l0 = *(const uint4*)pl;       l1 = *(const uint4*)(pl + 8);
        }
        int gc = col0 + trow;
        if (gc < Ncol) {
            const unsigned short* pb = Bhi + (size_t)gc * K + k0 + tcol;
            const unsigned short* pm = Blo + (size_t)gc * K + k0 + tcol;
            b0 = *(const uint4*)pb;       b1 = *(const uint4*)(pb + 8);
            m0 = *(const uint4*)pm;       m1 = *(const uint4*)(pm + 8);
        }
        __syncthreads();
        *(uint4*)&Ash[trow * LDP + tcol]     = a0;
        *(uint4*)&Ash[trow * LDP + tcol + 8] = a1;
        *(uint4*)&Asl[trow * LDP + tcol]     = l0;
        *(uint4*)&Asl[trow * LDP + tcol + 8] = l1;
        *(uint4*)&Bsh[trow * LDP + tcol]     = b0;
        *(uint4*)&Bsh[trow * LDP + tcol + 8] = b1;
        *(uint4*)&Bsl[trow * LDP + tcol]     = m0;
        *(uint4*)&Bsl[trow * LDP + tcol + 8] = m1;
        __syncthreads();

        bf16x8 vbh[4], vbl[4];
        #pragma unroll
        for (int nt = 0; nt < 4; ++nt) {
            vbh[nt] = *(const bf16x8*)&Bsh[(wc * 64 + nt * 16 + lrow) * LDP + kgrp];
            vbl[nt] = *(const bf16x8*)&Bsl[(wc * 64 + nt * 16 + lrow) * LDP + kgrp];
        }
        #pragma unroll
        for (int mt = 0; mt < 4; ++mt) {
            bf16x8 vah = *(const bf16x8*)&Ash[(wr * 64 + mt * 16 + lrow) * LDP + kgrp];
            bf16x8 val = *(const bf16x8*)&Asl[(wr * 64 + mt * 16 + lrow) * LDP + kgrp];
            #pragma unroll
            for (int nt = 0; nt < 4; ++nt) {
                acc[mt][nt] = __builtin_amdgcn_mfma_f32_16x16x32_bf16(vah, vbh[nt], acc[mt][nt], 0, 0, 0);
                acc[mt][nt] = __builtin_amdgcn_mfma_f32_16x16x32_bf16(val, vbh[nt], acc[mt][nt], 0, 0, 0);
                acc[mt][nt] = __builtin_amdgcn_mfma_f32_16x16x32_bf16(vah, vbl[nt], acc[mt][nt], 0, 0, 0);
            }
        }
    }

    int orow = (lane >> 4) * 4;
    #pragma unroll
    for (int mt = 0; mt < 4; ++mt) {
        #pragma unroll
        for (int nt = 0; nt < 4; ++nt) {
            int oc = col0 + wc * 64 + nt * 16 + lrow;
            #pragma unroll
            for (int rr = 0; rr < 4; ++rr) {
                int m = row0 + wr * 64 + mt * 16 + orow + rr;
                if (m < M) C[(size_t)m * ldc + oc] = (_Float16)acc[mt][nt][rr];
            }
        }
    }
}

static inline void gemm_split(const unsigned short* Ah, const unsigned short* Al,
                              const unsigned short* Bh, const unsigned short* Bl,
                              _Float16* C, int M, int Ncol, int K, int ldc, hipStream_t st) {
    if (Ncol == 256) {
        int Mb = (M + 127) / 128;
        k_gemm128<<<Mb * 2, 256, 0, st>>>(Ah, Al, Bh, Bl, C, M, Ncol, K, ldc);
    } else {
        int Mb = (M + 63) / 64, Nb = (Ncol + 63) / 64;
        k_gemm_split<<<dim3(Mb, Nb), 256, 0, st>>>(Ah, Al, Bh, Bl, C, M, Ncol, K, ldc);
    }
}

// ---------------- attention scores ----------------

// fused layer-0 scores for both branches: featC rows are [b0:256ch | b1:256ch],
// el8/er8 layout [i][h][b]
__global__ __launch_bounds__(256) void k_attn4x2(const _Float16* __restrict__ featC,
                                                 const float* __restrict__ a0l,
                                                 const float* __restrict__ a0r,
                                                 const float* __restrict__ a1l,
                                                 const float* __restrict__ a1r,
                                                 float* __restrict__ el8,
                                                 float* __restrict__ er8, int n) {
    int gw = blockIdx.x * 4 + (threadIdx.x >> 6);
    int lane = threadIdx.x & 63;
    int i = gw >> 3;
    if (i >= n) return;
    int rem = gw & 7;
    int b = rem >> 2, h = rem & 3;
    const float* al = b ? a1l : a0l;
    const float* ar = b ? a1r : a0r;
    float f = (float)featC[(size_t)i * 512 + b * 256 + h * 64 + lane];
    float pl = f * al[h * 64 + lane];
    float pr = f * ar[h * 64 + lane];
    #pragma unroll
    for (int off = 32; off; off >>= 1) {
        pl += __shfl_xor(pl, off);
        pr += __shfl_xor(pr, off);
    }
    if (lane == 0) {
        el8[i * 8 + h * 2 + b] = pl;
        er8[i * 8 + h * 2 + b] = pr;
    }
}

// fused 2-branch scores for H=1 layers: featC rows [b0:DB | b1:DB] f16
template <int DB>
__global__ __launch_bounds__(256) void k_attn2(const _Float16* __restrict__ feat,
                                               const float* __restrict__ al0,
                                               const float* __restrict__ ar0,
                                               const float* __restrict__ al1,
                                               const float* __restrict__ ar1,
                                               float* __restrict__ el2,
                                               float* __restrict__ er2, int n) {
    int gw = blockIdx.x * 4 + (threadIdx.x >> 6);
    int lane = threadIdx.x & 63;
    int i = gw >> 1, b = gw & 1;
    if (i >= n) return;
    bool act = lane < DB;
    float f = act ? (float)feat[(size_t)i * (2 * DB) + b * DB + lane] : 0.f;
    const float* al = b ? al1 : al0;
    const float* ar = b ? ar1 : ar0;
    float pl = act ? f * al[lane] : 0.f;
    float pr = act ? f * ar[lane] : 0.f;
    #pragma unroll
    for (int off = 32; off; off >>= 1) {
        pl += __shfl_xor(pl, off);
        pr += __shfl_xor(pr, off);
    }
    if (lane == 0) {
        el2[i * 2 + b] = pl;
        er2[i * 2 + b] = pr;
    }
}

__device__ __forceinline__ float lrelu(float v) { return v > 0.f ? v : 0.2f * v; }

// -------- FUSED H=4 aggregation for BOTH branches: ONE WAVE per dst -------
#define A42_ISSUE(J) uint4 q##J = *(const uint4*)(featLane + ((size_t)(unsigned)__shfl(s, (J) << 2) << 10))
#define A42_CONS(J, X) \
    FMAMIX_LO(f0, q##J.x, X); FMAMIX_HI(f1, q##J.x, X); \
    FMAMIX_LO(f2, q##J.y, X); FMAMIX_HI(f3, q##J.y, X); \
    FMAMIX_LO(f4, q##J.z, X); FMAMIX_HI(f5, q##J.z, X); \
    FMAMIX_LO(f6, q##J.w, X); FMAMIX_HI(f7, q##J.w, X)

__global__ __launch_bounds__(256) void k_agg4x2(const int* __restrict__ rowptr,
                                                const int* __restrict__ csr,
                                                const float* __restrict__ el8,
                                                const float* __restrict__ er8,
                                                const _Float16* __restrict__ featC,
                                                unsigned short* __restrict__ b0hi,
                                                unsigned short* __restrict__ b0lo,
                                                unsigned short* __restrict__ b1hi,
                                                unsigned short* __restrict__ b1lo,
                                                int n) {
    __shared__ float s_ex[4][128];  // [wave][b*64 + h*16 + eidx]
    int w = threadIdx.x >> 6;
    int lane = threadIdx.x & 63;
    int i = blockIdx.x * 4 + w;
    if (i >= n) return;
    int s0 = rowptr[i], s1 = rowptr[i + 1];
    int deg = s1 - s0;
    int eidx = lane >> 2, h = lane & 3;     // exp-stage role
    int b = lane >> 5, hh = (lane >> 3) & 3; // FMA/output-stage role
    float2 erp = *(const float2*)&er8[i * 8 + h * 2];  // (b0, b1) for head h
    const char* featLane = (const char*)featC + (lane << 4);

    float den0 = 0.f, den1 = 0.f;
    float m0 = -INFINITY, m1 = -INFINITY;
    float f0 = 0.f, f1 = 0.f, f2 = 0.f, f3 = 0.f;
    float f4 = 0.f, f5 = 0.f, f6 = 0.f, f7 = 0.f;

    int e0 = s0 + eidx;
    int s = (e0 < s1) ? csr[e0] : 0;
    for (int c = s0; c < s1; c += 16) {
        bool val = (c + eidx < s1);
        float2 elp = *(const float2*)&el8[(s << 3) + h * 2];
        A42_ISSUE(0);  A42_ISSUE(1);  A42_ISSUE(2);  A42_ISSUE(3);
        A42_ISSUE(4);  A42_ISSUE(5);  A42_ISSUE(6);  A42_ISSUE(7);
        A42_ISSUE(8);  A42_ISSUE(9);  A42_ISSUE(10); A42_ISSUE(11);
        A42_ISSUE(12); A42_ISSUE(13); A42_ISSUE(14); A42_ISSUE(15);
        int en = c + 16 + eidx;
        int sn = (en < s1) ? csr[en] : 0;
        float v0 = val ? lrelu(elp.x + erp.x) : -INFINITY;
        float v1 = val ? lrelu(elp.y + erp.y) : -INFINITY;
        float cm0 = v0, cm1 = v1;
        #pragma unroll
        for (int off = 4; off < 64; off <<= 1) {
            cm0 = fmaxf(cm0, __shfl_xor(cm0, off));
            cm1 = fmaxf(cm1, __shfl_xor(cm1, off));
        }
        float mn0 = fmaxf(m0, cm0), mn1 = fmaxf(m1, cm1);
        float sc0 = __expf(m0 - mn0), sc1 = __expf(m1 - mn1);
        m0 = mn0; m1 = mn1;
        float ex0 = val ? __expf(v0 - mn0) : 0.f;
        float ex1 = val ? __expf(v1 - mn1) : 0.f;
        den0 = den0 * sc0 + ex0;
        den1 = den1 * sc1 + ex1;
        s_ex[w][(h << 4) + eidx] = ex0;
        s_ex[w][64 + (h << 4) + eidx] = ex1;
        float sb0 = __shfl(sc0, hh), sb1 = __shfl(sc1, hh);
        float scl = (lane < 32) ? sb0 : sb1;
        f0 *= scl; f1 *= scl; f2 *= scl; f3 *= scl;
        f4 *= scl; f5 *= scl; f6 *= scl; f7 *= scl;
        const float* exrow = &s_ex[w][(b << 6) + (hh << 4)];
        float4 x0 = *(const float4*)&exrow[0];
        float4 x1 = *(const float4*)&exrow[4];
        float4 x2 = *(const float4*)&exrow[8];
        float4 x3 = *(const float4*)&exrow[12];
        A42_CONS(0, x0.x);  A42_CONS(1, x0.y);  A42_CONS(2, x0.z);  A42_CONS(3, x0.w);
        A42_CONS(4, x1.x);  A42_CONS(5, x1.y);  A42_CONS(6, x1.z);  A42_CONS(7, x1.w);
        A42_CONS(8, x2.x);  A42_CONS(9, x2.y);  A42_CONS(10, x2.z); A42_CONS(11, x2.w);
        A42_CONS(12, x3.x); A42_CONS(13, x3.y); A42_CONS(14, x3.z); A42_CONS(15, x3.w);
        s = sn;
    }

    #pragma unroll
    for (int off = 4; off < 64; off <<= 1) {
        den0 += __shfl_xor(den0, off);
        den1 += __shfl_xor(den1, off);
    }
    float db0 = __shfl(den0, hh), db1 = __shfl(den1, hh);
    float d = fmaxf((lane < 32) ? db0 : db1, 1e-9f);

    float o0 = (deg > 0) ? f0 / d : 0.f;
    float o1 = (deg > 0) ? f1 / d : 0.f;
    float o2 = (deg > 0) ? f2 / d : 0.f;
    float o3 = (deg > 0) ? f3 / d : 0.f;
    float o4 = (deg > 0) ? f4 / d : 0.f;
    float o5 = (deg > 0) ? f5 / d : 0.f;
    float o6 = (deg > 0) ? f6 / d : 0.f;
    float o7 = (deg > 0) ? f7 / d : 0.f;
    o0 = o0 > 0.f ? o0 : (__expf(o0) - 1.f);
    o1 = o1 > 0.f ? o1 : (__expf(o1) - 1.f);
    o2 = o2 > 0.f ? o2 : (__expf(o2) - 1.f);
    o3 = o3 > 0.f ? o3 : (__expf(o3) - 1.f);
    o4 = o4 > 0.f ? o4 : (__expf(o4) - 1.f);
    o5 = o5 > 0.f ? o5 : (__expf(o5) - 1.f);
    o6 = o6 > 0.f ? o6 : (__expf(o6) - 1.f);
    o7 = o7 > 0.f ? o7 : (__expf(o7) - 1.f);

    ushort4 vhA, vlA, vhB, vlB;
    split_bf(o0, vhA.x, vlA.x);
    split_bf(o1, vhA.y, vlA.y);
    split_bf(o2, vhA.z, vlA.z);
    split_bf(o3, vhA.w, vlA.w);
    split_bf(o4, vhB.x, vlB.x);
    split_bf(o5, vhB.y, vlB.y);
    split_bf(o6, vhB.z, vlB.z);
    split_bf(o7, vhB.w, vlB.w);
    size_t base = (size_t)i * 256 + ((lane & 31) << 3);
    if (lane < 32) {
        *(ushort4*)&b0hi[base] = vhA;  *(ushort4*)&b0hi[base + 4] = vhB;
        *(ushort4*)&b0lo[base] = vlA;  *(ushort4*)&b0lo[base + 4] = vlB;
    } else {
        *(ushort4*)&b1hi[base] = vhA;  *(ushort4*)&b1hi[base + 4] = vhB;
        *(ushort4*)&b1lo[base] = vlA;  *(ushort4*)&b1lo[base + 4] = vlB;
    }
}

// -------- FUSED 2-branch H=1 aggregation ----------------------------------
// featC rows = [b0:DB ch | b1:DB ch] f16 (4*DB bytes). Lane L gathers the
// dword covering combined channels (2L, 2L+1); lanes < DB/2 own branch 0,
// lanes in [DB/2, DB) own branch 1. Twin online-softmax chains; one csr/el
// pass serves both branches.
template <int DB, int ACT0, int ACT1, int SPLITOUT>
__global__ __launch_bounds__(256) void k_agg1x2(const int* __restrict__ rowptr,
                                                const int* __restrict__ csr,
                                                const float* __restrict__ el2,
                                                const float* __restrict__ er2,
                                                const _Float16* __restrict__ featC,
                                                unsigned short* __restrict__ o0hi,
                                                unsigned short* __restrict__ o0lo,
                                                unsigned short* __restrict__ o1hi,
                                                unsigned short* __restrict__ o1lo,
                                                float* __restrict__ ofp0,
                                                float* __restrict__ ofp1, int n) {
    __shared__ int   s_off[4][64];
    __shared__ float s_ex0[4][64];
    __shared__ float s_ex1[4][64];
    int w = threadIdx.x >> 6;
    int i = blockIdx.x * 4 + w;
    int lane = threadIdx.x & 63;
    if (i >= n) return;
    int s0 = rowptr[i], s1 = rowptr[i + 1];
    int deg = s1 - s0;
    float2 erp = *(const float2*)&er2[i * 2];
    bool act = lane < DB;
    int b = (lane >= (DB / 2)) ? 1 : 0;
    int loc = lane - b * (DB / 2);
    const char* featLane = (const char*)featC + lane * 4;
    const int ROWB = 4 * DB;

    float den0 = 0.f, den1 = 0.f, acc0 = 0.f, acc1 = 0.f;
    float m0 = -INFINITY, m1 = -INFINITY;

    auto fma_chunk = [&](int cnt) {
        const float* exr = b ? s_ex1[w] : s_ex0[w];
        int j = 0;
        for (; j + 4 <= cnt; j += 4) {
            int4   oj = *(const int4*)&s_off[w][j];
            float4 xj = *(const float4*)&exr[j];
            unsigned u0 = act ? *(const unsigned*)(featLane + oj.x) : 0u;
            unsigned u1 = act ? *(const unsigned*)(featLane + oj.y) : 0u;
            unsigned u2 = act ? *(const unsigned*)(featLane + oj.z) : 0u;
            unsigned u3 = act ? *(const unsigned*)(featLane + oj.w) : 0u;
            FMAMIX_LO(acc0, u0, xj.x); FMAMIX_HI(acc1, u0, xj.x);
            FMAMIX_LO(acc0, u1, xj.y); FMAMIX_HI(acc1, u1, xj.y);
            FMAMIX_LO(acc0, u2, xj.z); FMAMIX_HI(acc1, u2, xj.z);
            FMAMIX_LO(acc0, u3, xj.w); FMAMIX_HI(acc1, u3, xj.w);
        }
        for (; j < cnt; ++j) {
            unsigned u0 = act ? *(const unsigned*)(featLane + s_off[w][j]) : 0u;
            float x = exr[j];
            FMAMIX_LO(acc0, u0, x); FMAMIX_HI(acc1, u0, x);
        }
    };

    for (int c = s0; c < s1; c += 64) {
        int e = c + lane;
        bool val = e < s1;
        int s = 0;
        float2 elp = {0.f, 0.f};
        if (val) {
            s = csr[e];
            elp = *(const float2*)&el2[s * 2];
        }
        float v0 = val ? lrelu(elp.x + erp.x) : -INFINITY;
        float v1 = val ? lrelu(elp.y + erp.y) : -INFINITY;
        float cm0 = v0, cm1 = v1;
        #pragma unroll
        for (int off = 32; off; off >>= 1) {
            cm0 = fmaxf(cm0, __shfl_xor(cm0, off));
            cm1 = fmaxf(cm1, __shfl_xor(cm1, off));
        }
        float mn0 = fmaxf(m0, cm0), mn1 = fmaxf(m1, cm1);
        float sc0 = __expf(m0 - mn0), sc1 = __expf(m1 - mn1);
        m0 = mn0; m1 = mn1;
        float ex0 = val ? __expf(v0 - mn0) : 0.f;
        float ex1 = val ? __expf(v1 - mn1) : 0.f;
        den0 = den0 * sc0 + ex0;
        den1 = den1 * sc1 + ex1;
        float scl = b ? sc1 : sc0;
        acc0 *= scl; acc1 *= scl;
        s_off[w][lane] = s * ROWB;
        s_ex0[w][lane] = ex0;
        s_ex1[w][lane] = ex1;
        fma_chunk(min(64, s1 - c));
    }
    #pragma unroll
    for (int off = 32; off; off >>= 1) {
        den0 += __shfl_xor(den0, off);
        den1 += __shfl_xor(den1, off);
    }
    float d = fmaxf(b ? den1 : den0, 1e-9f);

    float o0 = (deg > 0) ? acc0 / d : 0.f;
    float o1 = (deg > 0) ? acc1 / d : 0.f;
    int actflag = b ? ACT1 : ACT0;
    if (actflag) {
        o0 = o0 > 0.f ? o0 : (__expf(o0) - 1.f);
        o1 = o1 > 0.f ? o1 : (__expf(o1) - 1.f);
    }
    if (act) {
        if (SPLITOUT) {
            unsigned short h0, l0, h1, l1;
            split_bf(o0, h0, l0);
            split_bf(o1, h1, l1);
            ushort2 vh = {h0, h1}, vl = {l0, l1};
            if (b == 0) {
                *(ushort2*)&o0hi[(size_t)i * DB + 2 * loc] = vh;
                *(ushort2*)&o0lo[(size_t)i * DB + 2 * loc] = vl;
            } else {
                *(ushort2*)&o1hi[(size_t)i * DB + 2 * loc] = vh;
                *(ushort2*)&o1lo[(size_t)i * DB + 2 * loc] = vl;
            }
        } else {
            float2 vo = {o0, o1};
            if (b == 0) *(float2*)&ofp0[(size_t)i * DB + 2 * loc] = vo;
            else        *(float2*)&ofp1[(size_t)i * DB + 2 * loc] = vo;
        }
    }
}

// ---------------- launch ----------------

extern "C" void kernel_launch(void* const* d_in, const int* in_sizes, int n_in,
                              void* d_out, int out_size, void* d_ws, size_t ws_size,
                              hipStream_t stream) {
    const float* x    = (const float*)d_in[0];
    const int*   src  = (const int*)d_in[1];
    const int*   dst  = (const int*)d_in[2];
    const float* W00  = (const float*)d_in[3];
    const float* a00l = (const float*)d_in[4];
    const float* a00r = (const float*)d_in[5];
    const float* W01  = (const float*)d_in[6];
    const float* a01l = (const float*)d_in[7];
    const float* a01r = (const float*)d_in[8];
    const float* W0f  = (const float*)d_in[9];
    const float* a0fl = (const float*)d_in[10];
    const float* a0fr = (const float*)d_in[11];
    const float* W10  = (const float*)d_in[12];
    const float* a10l = (const float*)d_in[13];
    const float* a10r = (const float*)d_in[14];
    const float* W1f  = (const float*)d_in[15];
    const float* a1fl = (const float*)d_in[16];
    const float* a1fr = (const float*)d_in[17];
    const float* W1o  = (const float*)d_in[18];
    const float* a1ol = (const float*)d_in[19];
    const float* a1or = (const float*)d_in[20];
    float* out = (float*)d_out;

    const int n = in_sizes[0] / 256;  // 50000
    const int e = in_sizes[1];        // 800000
    const int C = 40;

    char* p = (char*)d_ws;
    auto alloc = [&](size_t bytes) -> void* {
        void* r = (void*)p;
        p += (bytes + 255) & ~(size_t)255;
        return r;
    };
    int*   deg     = (int*)alloc((size_t)n * 4);
    int*   tmp     = (int*)alloc((size_t)n * 4);
    int*   bsum    = (int*)alloc(64 * 4);
    int*   rowptr  = (int*)alloc((size_t)(n + 1) * 4);
    int*   cursor  = (int*)alloc((size_t)n * 4);
    int*   csr     = (int*)alloc((size_t)e * 4);
    float* el8     = (float*)alloc((size_t)n * 8 * 4);
    float* er8     = (float*)alloc((size_t)n * 8 * 4);
    _Float16* featC = (_Float16*)alloc((size_t)n * 512 * 2 + 256);
    unsigned short* xhi = (unsigned short*)alloc((size_t)n * 256 * 2);  // x split; reused for branch1 feats
    unsigned short* xlo = (unsigned short*)alloc((size_t)n * 256 * 2);
    unsigned short* hhi = (unsigned short*)alloc((size_t)n * 256 * 2);  // branch0 feats
    unsigned short* hlo = (unsigned short*)alloc((size_t)n * 256 * 2);
    unsigned short* W00h = (unsigned short*)alloc(256 * 256 * 2);
    unsigned short* W00l = (unsigned short*)alloc(256 * 256 * 2);
    unsigned short* W01h = (unsigned short*)alloc(256 * 64 * 2);
    unsigned short* W01l = (unsigned short*)alloc(256 * 64 * 2);
    unsigned short* W0fh = (unsigned short*)alloc(64 * 40 * 2);
    unsigned short* W0fl = (unsigned short*)alloc(64 * 40 * 2);
    unsigned short* W10h = (unsigned short*)alloc(256 * 256 * 2);
    unsigned short* W10l = (unsigned short*)alloc(256 * 256 * 2);
    unsigned short* W1fh = (unsigned short*)alloc(256 * 64 * 2);
    unsigned short* W1fl = (unsigned short*)alloc(256 * 64 * 2);
    unsigned short* W1oh = (unsigned short*)alloc(64 * 40 * 2);
    unsigned short* W1ol = (unsigned short*)alloc(64 * 40 * 2);

    // ---- CSR build ----
    hipMemsetAsync(deg, 0, (size_t)n * 4, stream);
    k_hist<<<(e + 255) / 256, 256, 0, stream>>>(dst, deg, e);
    int nb = (n + 1023) / 1024;
    k_scan1<<<nb, 1024, 0, stream>>>(deg, tmp, bsum, n);
    k_scan2<<<1, 1, 0, stream>>>(bsum, nb);
    k_scan3<<<(n + 255) / 256, 256, 0, stream>>>(deg, tmp, bsum, rowptr, cursor, n);
    k_scatter<<<(e + 255) / 256, 256, 0, stream>>>(src, dst, cursor, csr, e);

    // ---- casts ----
    int nel = n * 256;
    k_castx<<<(nel / 4 + 255) / 256, 256, 0, stream>>>(x, xhi, xlo, nel / 4);
    k_castw<<<(256 * 256 + 255) / 256, 256, 0, stream>>>(W00, W00h, W00l, 256, 256);
    k_castw<<<(256 * 64 + 255) / 256, 256, 0, stream>>>(W01, W01h, W01l, 256, 64);
    k_castw<<<(64 * 40 + 255) / 256, 256, 0, stream>>>(W0f, W0fh, W0fl, 64, 40);
    k_castw<<<(256 * 256 + 255) / 256, 256, 0, stream>>>(W10, W10h, W10l, 256, 256);
    k_castw<<<(256 * 64 + 255) / 256, 256, 0, stream>>>(W1f, W1fh, W1fl, 256, 64);
    k_castw<<<(64 * 40 + 255) / 256, 256, 0, stream>>>(W1o, W1oh, W1ol, 64, 40);

    int gw1 = (n + 3) / 4;

    // ---- fused layer 0 (both branches) ----
    gemm_split(xhi, xlo, W00h, W00l, featC,       n, 256, 256, 512, stream);
    gemm_split(xhi, xlo, W10h, W10l, featC + 256, n, 256, 256, 512, stream);
    k_attn4x2<<<(n * 8 + 3) / 4, 256, 0, stream>>>(featC, a00l, a00r, a10l, a10r, el8, er8, n);
    // b0 h -> hhi/hlo, b1 h -> xhi/xlo (x split dead after L0 GEMMs)
    k_agg4x2<<<gw1, 256, 0, stream>>>(rowptr, csr, el8, er8, featC, hhi, hlo, xhi, xlo, n);

    // ---- fused mid layer (b0 L1 elu | b1 encoder-final no-act) ----
    gemm_split(hhi, hlo, W01h, W01l, featC,      n, 64, 256, 128, stream);
    gemm_split(xhi, xlo, W1fh, W1fl, featC + 64, n, 64, 256, 128, stream);
    k_attn2<64><<<(n * 2 + 3) / 4, 256, 0, stream>>>(featC, a01l, a01r, a1fl, a1fr, el8, er8, n);
    k_agg1x2<64, 1, 0, 1><<<gw1, 256, 0, stream>>>(rowptr, csr, el8, er8, featC,
                                                   hhi, hlo, xhi, xlo, nullptr, nullptr, n);

    // ---- fused final layer (b0 no-act | b1 elu) ----
    gemm_split(hhi, hlo, W0fh, W0fl, featC,      n, C, 64, 80, stream);
    gemm_split(xhi, xlo, W1oh, W1ol, featC + 40, n, C, 64, 80, stream);
    k_attn2<40><<<(n * 2 + 3) / 4, 256, 0, stream>>>(featC, a0fl, a0fr, a1ol, a1or, el8, er8, n);
    k_agg1x2<40, 0, 1, 0><<<gw1, 256, 0, stream>>>(rowptr, csr, el8, er8, featC,
                                                   nullptr, nullptr, nullptr, nullptr,
                                                   out, out + (size_t)n * C, n);
}

// Round 6
// 583.581 us; speedup vs baseline: 1.2668x; 1.1086x over previous
//
#include <hip/hip_runtime.h>
#include <math.h>

typedef __attribute__((ext_vector_type(8))) short bf16x8;
typedef __attribute__((ext_vector_type(4))) float f32x4;

// f32 += f16(lo/hi half of packed dword) * f32  -- exact, single VOP3P instr
#define FMAMIX_LO(acc, pk, s) \
    asm("v_fma_mix_f32 %0, %1, %2, %0 op_sel:[0,0,0] op_sel_hi:[1,0,0]" \
        : "+v"(acc) : "v"(pk), "v"(s))
#define FMAMIX_HI(acc, pk, s) \
    asm("v_fma_mix_f32 %0, %1, %2, %0 op_sel:[1,0,0] op_sel_hi:[1,0,0]" \
        : "+v"(acc) : "v"(pk), "v"(s))

__device__ __forceinline__ unsigned short f2bf(float f) {
    unsigned int u = __float_as_uint(f);
    unsigned int r = (u + 0x7FFF + ((u >> 16) & 1)) >> 16;  // RNE
    return (unsigned short)r;
}
__device__ __forceinline__ float bf2f(unsigned short h) {
    return __uint_as_float((unsigned int)h << 16);
}
__device__ __forceinline__ void split_bf(float x, unsigned short& hi, unsigned short& lo) {
    hi = f2bf(x);
    lo = f2bf(x - bf2f(hi));
}

// ---------------- CSR build ----------------

__global__ void k_hist(const int* __restrict__ dst, int* __restrict__ deg, int e) {
    int t = blockIdx.x * 256 + threadIdx.x;
    if (t < e) atomicAdd(&deg[dst[t]], 1);
}

__global__ void k_scan1(const int* __restrict__ deg, int* __restrict__ tmp,
                        int* __restrict__ bsum, int n) {
    __shared__ int s[1024];
    int t = threadIdx.x;
    int g = blockIdx.x * 1024 + t;
    int v = (g < n) ? deg[g] : 0;
    s[t] = v;
    __syncthreads();
    for (int off = 1; off < 1024; off <<= 1) {
        int u = (t >= off) ? s[t - off] : 0;
        __syncthreads();
        s[t] += u;
        __syncthreads();
    }
    if (g < n) tmp[g] = s[t];
    if (t == 1023) bsum[blockIdx.x] = s[t];
}

__global__ void k_scan2(int* bsum, int nb) {
    int acc = 0;
    for (int b = 0; b < nb; ++b) { int v = bsum[b]; bsum[b] = acc; acc += v; }
}

__global__ void k_scan3(const int* __restrict__ deg, const int* __restrict__ tmp,
                        const int* __restrict__ bsum, int* __restrict__ rowptr,
                        int* __restrict__ cursor, int n) {
    int g = blockIdx.x * 256 + threadIdx.x;
    if (g < n) {
        int incl = tmp[g] + bsum[g >> 10];
        rowptr[g + 1] = incl;
        cursor[g] = incl - deg[g];
        if (g == 0) rowptr[0] = 0;
    }
}

__global__ void k_scatter(const int* __restrict__ src, const int* __restrict__ dst,
                          int* __restrict__ cursor, int* __restrict__ csr, int e) {
    int t = blockIdx.x * 256 + threadIdx.x;
    if (t < e) {
        int d = dst[t];
        int pos = atomicAdd(&cursor[d], 1);
        csr[pos] = src[t];
    }
}

// ---------------- casts (split hi/lo) ----------------

__global__ void k_castx(const float* __restrict__ x, unsigned short* __restrict__ xhi,
                        unsigned short* __restrict__ xlo, int nvec) {
    int t = blockIdx.x * 256 + threadIdx.x;
    if (t < nvec) {
        float4 v = ((const float4*)x)[t];
        ushort4 h, l;
        split_bf(v.x, h.x, l.x);
        split_bf(v.y, h.y, l.y);
        split_bf(v.z, h.z, l.z);
        split_bf(v.w, h.w, l.w);
        ((ushort4*)xhi)[t] = h;
        ((ushort4*)xlo)[t] = l;
    }
}

// one dispatch casts+transposes all 6 weight matrices
struct WSeg { const float* W; unsigned short* Wh; unsigned short* Wl; int K; int N; int cnt; };
__global__ void k_castw_all(WSeg s0, WSeg s1, WSeg s2, WSeg s3, WSeg s4, WSeg s5) {
    int t = blockIdx.x * 256 + threadIdx.x;
    WSeg sg;
    if      (t < s0.cnt) { sg = s0; }
    else if ((t -= s0.cnt) < s1.cnt) { sg = s1; }
    else if ((t -= s1.cnt) < s2.cnt) { sg = s2; }
    else if ((t -= s2.cnt) < s3.cnt) { sg = s3; }
    else if ((t -= s3.cnt) < s4.cnt) { sg = s4; }
    else if ((t -= s4.cnt) < s5.cnt) { sg = s5; }
    else return;
    int k = t / sg.N, n = t - k * sg.N;
    unsigned short h, l;
    split_bf(sg.W[t], h, l);
    sg.Wh[n * sg.K + k] = h;
    sg.Wl[n * sg.K + k] = l;
}

// ------- split-bf16 MFMA GEMM (NT): C = A @ Bt^T, ~fp32 accuracy ----------
// Output fp16 with row stride ldc. FUSED attn epilogue: computes
// el[m] = sum_c C[m,c]*al[c], er likewise, stored to el2/er2 at [m*8 + h*2 + bsel]
// (k_gemm128, per-head) or [m*2 + bsel] (k_gemm_split, H=1).

#define LDP 40

// 64x64-tile kernel (Ncol <= 64, H=1). Cross-wave attn reduce via LDS.
__global__ __launch_bounds__(256) void k_gemm_split(const unsigned short* __restrict__ Ahi,
                                                    const unsigned short* __restrict__ Alo,
                                                    const unsigned short* __restrict__ Bhi,
                                                    const unsigned short* __restrict__ Blo,
                                                    _Float16* __restrict__ C,
                                                    int M, int Ncol, int K, int ldc,
                                                    const float* __restrict__ al,
                                                    const float* __restrict__ ar,
                                                    float* __restrict__ el2,
                                                    float* __restrict__ er2, int bsel) {
    int bx = blockIdx.x, by = blockIdx.y;
    __shared__ unsigned short Ash[64 * LDP];
    __shared__ unsigned short Asl[64 * LDP];
    __shared__ unsigned short Bsh[64 * LDP];
    __shared__ unsigned short Bsl[64 * LDP];
    int t = threadIdx.x;
    int w = t >> 6, lane = t & 63;
    int lrow = lane & 15, kgrp = (lane >> 4) * 8;
    int row0 = bx * 64, col0 = by * 64;
    int trow = t >> 2, tcol = (t & 3) * 8;

    f32x4 acc[4] = {{0.f, 0.f, 0.f, 0.f}, {0.f, 0.f, 0.f, 0.f},
                    {0.f, 0.f, 0.f, 0.f}, {0.f, 0.f, 0.f, 0.f}};

    for (int k0 = 0; k0 < K; k0 += 32) {
        uint4 ah = {0u,0u,0u,0u}, al4 = {0u,0u,0u,0u};
        uint4 bh = {0u,0u,0u,0u}, bl4 = {0u,0u,0u,0u};
        int gr = row0 + trow;
        if (gr < M) {
            ah  = *(const uint4*)(Ahi + (size_t)gr * K + k0 + tcol);
            al4 = *(const uint4*)(Alo + (size_t)gr * K + k0 + tcol);
        }
        int gc = col0 + trow;
        if (gc < Ncol) {
            bh  = *(const uint4*)(Bhi + (size_t)gc * K + k0 + tcol);
            bl4 = *(const uint4*)(Blo + (size_t)gc * K + k0 + tcol);
        }
        __syncthreads();
        *(uint4*)&Ash[trow * LDP + tcol] = ah;
        *(uint4*)&Asl[trow * LDP + tcol] = al4;
        *(uint4*)&Bsh[trow * LDP + tcol] = bh;
        *(uint4*)&Bsl[trow * LDP + tcol] = bl4;
        __syncthreads();
        bf16x8 vbh = *(const bf16x8*)&Bsh[(w * 16 + lrow) * LDP + kgrp];
        bf16x8 vbl = *(const bf16x8*)&Bsl[(w * 16 + lrow) * LDP + kgrp];
        #pragma unroll
        for (int mt = 0; mt < 4; ++mt) {
            bf16x8 vah = *(const bf16x8*)&Ash[(mt * 16 + lrow) * LDP + kgrp];
            bf16x8 val = *(const bf16x8*)&Asl[(mt * 16 + lrow) * LDP + kgrp];
            acc[mt] = __builtin_amdgcn_mfma_f32_16x16x32_bf16(vah, vbh, acc[mt], 0, 0, 0);
            acc[mt] = __builtin_amdgcn_mfma_f32_16x16x32_bf16(val, vbh, acc[mt], 0, 0, 0);
            acc[mt] = __builtin_amdgcn_mfma_f32_16x16x32_bf16(vah, vbl, acc[mt], 0, 0, 0);
        }
    }

    int ocol = col0 + w * 16 + lrow;
    int orow = (lane >> 4) * 4;
    if (ocol < Ncol) {
        #pragma unroll
        for (int mt = 0; mt < 4; ++mt) {
            #pragma unroll
            for (int r = 0; r < 4; ++r) {
                int m = row0 + mt * 16 + orow + r;
                if (m < M) C[(size_t)m * ldc + ocol] = (_Float16)acc[mt][r];
            }
        }
    }

    // ---- fused H=1 attn epilogue ----
    float alv = (ocol < Ncol) ? al[ocol] : 0.f;
    float arv = (ocol < Ncol) ? ar[ocol] : 0.f;
    __syncthreads();
    float* Pl = (float*)Ash;   // [4 waves][64 rows]
    float* Pr = (float*)Bsh;
    #pragma unroll
    for (int mt = 0; mt < 4; ++mt) {
        #pragma unroll
        for (int r = 0; r < 4; ++r) {
            float pl = acc[mt][r] * alv;
            float pr = acc[mt][r] * arv;
            #pragma unroll
            for (int off = 1; off < 16; off <<= 1) {
                pl += __shfl_xor(pl, off);
                pr += __shfl_xor(pr, off);
            }
            if (lrow == 0) {
                int rloc = mt * 16 + orow + r;
                Pl[w * 64 + rloc] = pl;
                Pr[w * 64 + rloc] = pr;
            }
        }
    }
    __syncthreads();
    if (t < 64) {
        int m = row0 + t;
        if (m < M) {
            float pl = Pl[t] + Pl[64 + t] + Pl[128 + t] + Pl[192 + t];
            float pr = Pr[t] + Pr[64 + t] + Pr[128 + t] + Pr[192 + t];
            el2[m * 2 + bsel] = pl;
            er2[m * 2 + bsel] = pr;
        }
    }
}

// 128x128-tile kernel for Ncol==256. Bijective XCD-chunk swizzle.
// Each wave's tile covers one full head (64 cols) -> in-wave attn reduce.
__global__ __launch_bounds__(256) void k_gemm128(const unsigned short* __restrict__ Ahi,
                                                 const unsigned short* __restrict__ Alo,
                                                 const unsigned short* __restrict__ Bhi,
                                                 const unsigned short* __restrict__ Blo,
                                                 _Float16* __restrict__ C,
                                                 int M, int Ncol, int K, int ldc,
                                                 const float* __restrict__ al,
                                                 const float* __restrict__ ar,
                                                 float* __restrict__ el8,
                                                 float* __restrict__ er8, int bsel) {
    int Mb = (M + 127) >> 7;
    int nwg = Mb * 2;
    int v = blockIdx.x;
    int q = nwg >> 3, r = nwg & 7;
    int xcd = v & 7, idx = v >> 3;
    int wg = (xcd < r ? xcd * (q + 1) : r * (q + 1) + (xcd - r) * q) + idx;
    int bx = wg >> 1, by = wg & 1;
    int row0 = bx * 128, col0 = by * 128;

    __shared__ unsigned short Ash[128 * LDP];
    __shared__ unsigned short Asl[128 * LDP];
    __shared__ unsigned short Bsh[128 * LDP];
    __shared__ unsigned short Bsl[128 * LDP];

    int t = threadIdx.x;
    int w = t >> 6, lane = t & 63;
    int wr = w >> 1, wc = w & 1;
    int lrow = lane & 15, kgrp = (lane >> 4) * 8;
    int trow = t >> 1, tcol = (t & 1) * 16;

    f32x4 acc[4][4];
    #pragma unroll
    for (int mt = 0; mt < 4; ++mt)
        #pragma unroll
        for (int nt = 0; nt < 4; ++nt)
            acc[mt][nt] = (f32x4){0.f, 0.f, 0.f, 0.f};

    for (int k0 = 0; k0 < K; k0 += 32) {
        uint4 a0 = {0u,0u,0u,0u}, a1 = {0u,0u,0u,0u};
        uint4 l0 = {0u,0u,0u,0u}, l1 = {0u,0u,0u,0u};
        uint4 b0 = {0u,0u,0u,0u}, b1 = {0u,0u,0u,0u};
        uint4 m0 = {0u,0u,0u,0u}, m1 = {0u,0u,0u,0u};
        int gr = row0 + trow;
        if (gr < M) {
            const unsigned short* pa = Ahi + (size_t)gr * K + k0 + tcol;
            const unsigned short* pl = Alo + (size_t)gr * K + k0 + tcol;
            a0 = *(const uint4*)pa;       a1 = *(const uint4*)(pa + 8);
            l0 = *(const uint4*)pl;       l1 = *(const uint4*)(pl + 8);
        }
        int gc = col0 + trow;
        if (gc < Ncol) {
            const unsigned short* pb = Bhi + (size_t)gc * K + k0 + tcol;
            const unsigned short* pm = Blo + (size_t)gc * K + k0 + tcol;
            b0 = *(const uint4*)pb;       b1 = *(const uint4*)(pb + 8);
            m0 = *(const uint4*)pm;       m1 = *(const uint4*)(pm + 8);
        }
        __syncthreads();
        *(uint4*)&Ash[trow * LDP + tcol]     = a0;
        *(uint4*)&Ash[trow * LDP + tcol + 8] = a1;
        *(uint4*)&Asl[trow * LDP + tcol]     = l0;
        *(uint4*)&Asl[trow * LDP + tcol + 8] = l1;
        *(uint4*)&Bsh[trow * LDP + tcol]     = b0;
        *(uint4*)&Bsh[trow * LDP + tcol + 8] = b1;
        *(uint4*)&Bsl[trow * LDP + tcol]     = m0;
        *(uint4*)&Bsl[trow * LDP + tcol + 8] = m1;
        __syncthreads();

        bf16x8 vbh[4], vbl[4];
        #pragma unroll
        for (int nt = 0; nt < 4; ++nt) {
            vbh[nt] = *(const bf16x8*)&Bsh[(wc * 64 + nt * 16 + lrow) * LDP + kgrp];
            vbl[nt] = *(const bf16x8*)&Bsl[(wc * 64 + nt * 16 + lrow) * LDP + kgrp];
        }
        #pragma unroll
        for (int mt = 0; mt < 4; ++mt) {
            bf16x8 vah = *(const bf16x8*)&Ash[(wr * 64 + mt * 16 + lrow) * LDP + kgrp];
            bf16x8 val = *(const bf16x8*)&Asl[(wr * 64 + mt * 16 + lrow) * LDP + kgrp];
            #pragma unroll
            for (int nt = 0; nt < 4; ++nt) {
                acc[mt][nt] = __builtin_amdgcn_mfma_f32_16x16x32_bf16(vah, vbh[nt], acc[mt][nt], 0, 0, 0);
                acc[mt][nt] = __builtin_amdgcn_mfma_f32_16x16x32_bf16(val, vbh[nt], acc[mt][nt], 0, 0, 0);
                acc[mt][nt] = __builtin_amdgcn_mfma_f32_16x16x32_bf16(vah, vbl[nt], acc[mt][nt], 0, 0, 0);
            }
        }
    }

    int orow = (lane >> 4) * 4;
    #pragma unroll
    for (int mt = 0; mt < 4; ++mt) {
        #pragma unroll
        for (int nt = 0; nt < 4; ++nt) {
            int oc = col0 + wc * 64 + nt * 16 + lrow;
            #pragma unroll
            for (int rr = 0; rr < 4; ++rr) {
                int m = row0 + wr * 64 + mt * 16 + orow + rr;
                if (m < M) C[(size_t)m * ldc + oc] = (_Float16)acc[mt][nt][rr];
            }
        }
    }

    // ---- fused per-head attn epilogue (head = by*2+wc, cols nt*16+lrow) ----
    int h = by * 2 + wc;
    float alv[4], arv[4];
    #pragma unroll
    for (int nt = 0; nt < 4; ++nt) {
        int cidx = nt * 16 + lrow;
        alv[nt] = al[h * 64 + cidx];
        arv[nt] = ar[h * 64 + cidx];
    }
    #pragma unroll
    for (int mt = 0; mt < 4; ++mt) {
        #pragma unroll
        for (int rr = 0; rr < 4; ++rr) {
            float pl = 0.f, pr = 0.f;
            #pragma unroll
            for (int nt = 0; nt < 4; ++nt) {
                pl = fmaf(acc[mt][nt][rr], alv[nt], pl);
                pr = fmaf(acc[mt][nt][rr], arv[nt], pr);
            }
            #pragma unroll
            for (int off = 1; off < 16; off <<= 1) {
                pl += __shfl_xor(pl, off);
                pr += __shfl_xor(pr, off);
            }
            int m = row0 + wr * 64 + mt * 16 + orow + rr;
            if (lrow == 0 && m < M) {
                el8[m * 8 + h * 2 + bsel] = pl;
                er8[m * 8 + h * 2 + bsel] = pr;
            }
        }
    }
}

static inline void gemm_split(const unsigned short* Ah, const unsigned short* Al,
                              const unsigned short* Bh, const unsigned short* Bl,
                              _Float16* C, int M, int Ncol, int K, int ldc,
                              const float* al, const float* ar,
                              float* el, float* er, int bsel, hipStream_t st) {
    if (Ncol == 256) {
        int Mb = (M + 127) / 128;
        k_gemm128<<<Mb * 2, 256, 0, st>>>(Ah, Al, Bh, Bl, C, M, Ncol, K, ldc,
                                          al, ar, el, er, bsel);
    } else {
        int Mb = (M + 63) / 64, Nb = (Ncol + 63) / 64;
        k_gemm_split<<<dim3(Mb, Nb), 256, 0, st>>>(Ah, Al, Bh, Bl, C, M, Ncol, K, ldc,
                                                   al, ar, el, er, bsel);
    }
}

__device__ __forceinline__ float lrelu(float v) { return v > 0.f ? v : 0.2f * v; }

// -------- FUSED H=4 aggregation for BOTH branches: ONE WAVE per dst -------
#define A42_ISSUE(J) uint4 q##J = *(const uint4*)(featLane + ((size_t)(unsigned)__shfl(s, (J) << 2) << 10))
#define A42_CONS(J, X) \
    FMAMIX_LO(f0, q##J.x, X); FMAMIX_HI(f1, q##J.x, X); \
    FMAMIX_LO(f2, q##J.y, X); FMAMIX_HI(f3, q##J.y, X); \
    FMAMIX_LO(f4, q##J.z, X); FMAMIX_HI(f5, q##J.z, X); \
    FMAMIX_LO(f6, q##J.w, X); FMAMIX_HI(f7, q##J.w, X)

__global__ __launch_bounds__(256) void k_agg4x2(const int* __restrict__ rowptr,
                                                const int* __restrict__ csr,
                                                const float* __restrict__ el8,
                                                const float* __restrict__ er8,
                                                const _Float16* __restrict__ featC,
                                                unsigned short* __restrict__ b0hi,
                                                unsigned short* __restrict__ b0lo,
                                                unsigned short* __restrict__ b1hi,
                                                unsigned short* __restrict__ b1lo,
                                                int n) {
    __shared__ float s_ex[4][128];  // [wave][b*64 + h*16 + eidx]
    int w = threadIdx.x >> 6;
    int lane = threadIdx.x & 63;
    int i = blockIdx.x * 4 + w;
    if (i >= n) return;
    int s0 = rowptr[i], s1 = rowptr[i + 1];
    int deg = s1 - s0;
    int eidx = lane >> 2, h = lane & 3;     // exp-stage role
    int b = lane >> 5, hh = (lane >> 3) & 3; // FMA/output-stage role
    float2 erp = *(const float2*)&er8[i * 8 + h * 2];  // (b0, b1) for head h
    const char* featLane = (const char*)featC + (lane << 4);

    float den0 = 0.f, den1 = 0.f;
    float m0 = -INFINITY, m1 = -INFINITY;
    float f0 = 0.f, f1 = 0.f, f2 = 0.f, f3 = 0.f;
    float f4 = 0.f, f5 = 0.f, f6 = 0.f, f7 = 0.f;

    int e0 = s0 + eidx;
    int s = (e0 < s1) ? csr[e0] : 0;
    for (int c = s0; c < s1; c += 16) {
        bool val = (c + eidx < s1);
        float2 elp = *(const float2*)&el8[(s << 3) + h * 2];
        A42_ISSUE(0);  A42_ISSUE(1);  A42_ISSUE(2);  A42_ISSUE(3);
        A42_ISSUE(4);  A42_ISSUE(5);  A42_ISSUE(6);  A42_ISSUE(7);
        A42_ISSUE(8);  A42_ISSUE(9);  A42_ISSUE(10); A42_ISSUE(11);
        A42_ISSUE(12); A42_ISSUE(13); A42_ISSUE(14); A42_ISSUE(15);
        int en = c + 16 + eidx;
        int sn = (en < s1) ? csr[en] : 0;
        float v0 = val ? lrelu(elp.x + erp.x) : -INFINITY;
        float v1 = val ? lrelu(elp.y + erp.y) : -INFINITY;
        float cm0 = v0, cm1 = v1;
        #pragma unroll
        for (int off = 4; off < 64; off <<= 1) {
            cm0 = fmaxf(cm0, __shfl_xor(cm0, off));
            cm1 = fmaxf(cm1, __shfl_xor(cm1, off));
        }
        float mn0 = fmaxf(m0, cm0), mn1 = fmaxf(m1, cm1);
        float sc0 = __expf(m0 - mn0), sc1 = __expf(m1 - mn1);
        m0 = mn0; m1 = mn1;
        float ex0 = val ? __expf(v0 - mn0) : 0.f;
        float ex1 = val ? __expf(v1 - mn1) : 0.f;
        den0 = den0 * sc0 + ex0;
        den1 = den1 * sc1 + ex1;
        s_ex[w][(h << 4) + eidx] = ex0;
        s_ex[w][64 + (h << 4) + eidx] = ex1;
        float sb0 = __shfl(sc0, hh), sb1 = __shfl(sc1, hh);
        float scl = (lane < 32) ? sb0 : sb1;
        f0 *= scl; f1 *= scl; f2 *= scl; f3 *= scl;
        f4 *= scl; f5 *= scl; f6 *= scl; f7 *= scl;
        const float* exrow = &s_ex[w][(b << 6) + (hh << 4)];
        float4 x0 = *(const float4*)&exrow[0];
        float4 x1 = *(const float4*)&exrow[4];
        float4 x2 = *(const float4*)&exrow[8];
        float4 x3 = *(const float4*)&exrow[12];
        A42_CONS(0, x0.x);  A42_CONS(1, x0.y);  A42_CONS(2, x0.z);  A42_CONS(3, x0.w);
        A42_CONS(4, x1.x);  A42_CONS(5, x1.y);  A42_CONS(6, x1.z);  A42_CONS(7, x1.w);
        A42_CONS(8, x2.x);  A42_CONS(9, x2.y);  A42_CONS(10, x2.z); A42_CONS(11, x2.w);
        A42_CONS(12, x3.x); A42_CONS(13, x3.y); A42_CONS(14, x3.z); A42_CONS(15, x3.w);
        s = sn;
    }

    #pragma unroll
    for (int off = 4; off < 64; off <<= 1) {
        den0 += __shfl_xor(den0, off);
        den1 += __shfl_xor(den1, off);
    }
    float db0 = __shfl(den0, hh), db1 = __shfl(den1, hh);
    float d = fmaxf((lane < 32) ? db0 : db1, 1e-9f);

    float o0 = (deg > 0) ? f0 / d : 0.f;
    float o1 = (deg > 0) ? f1 / d : 0.f;
    float o2 = (deg > 0) ? f2 / d : 0.f;
    float o3 = (deg > 0) ? f3 / d : 0.f;
    float o4 = (deg > 0) ? f4 / d : 0.f;
    float o5 = (deg > 0) ? f5 / d : 0.f;
    float o6 = (deg > 0) ? f6 / d : 0.f;
    float o7 = (deg > 0) ? f7 / d : 0.f;
    o0 = o0 > 0.f ? o0 : (__expf(o0) - 1.f);
    o1 = o1 > 0.f ? o1 : (__expf(o1) - 1.f);
    o2 = o2 > 0.f ? o2 : (__expf(o2) - 1.f);
    o3 = o3 > 0.f ? o3 : (__expf(o3) - 1.f);
    o4 = o4 > 0.f ? o4 : (__expf(o4) - 1.f);
    o5 = o5 > 0.f ? o5 : (__expf(o5) - 1.f);
    o6 = o6 > 0.f ? o6 : (__expf(o6) - 1.f);
    o7 = o7 > 0.f ? o7 : (__expf(o7) - 1.f);

    ushort4 vhA, vlA, vhB, vlB;
    split_bf(o0, vhA.x, vlA.x);
    split_bf(o1, vhA.y, vlA.y);
    split_bf(o2, vhA.z, vlA.z);
    split_bf(o3, vhA.w, vlA.w);
    split_bf(o4, vhB.x, vlB.x);
    split_bf(o5, vhB.y, vlB.y);
    split_bf(o6, vhB.z, vlB.z);
    split_bf(o7, vhB.w, vlB.w);
    size_t base = (size_t)i * 256 + ((lane & 31) << 3);
    if (lane < 32) {
        *(ushort4*)&b0hi[base] = vhA;  *(ushort4*)&b0hi[base + 4] = vhB;
        *(ushort4*)&b0lo[base] = vlA;  *(ushort4*)&b0lo[base + 4] = vlB;
    } else {
        *(ushort4*)&b1hi[base] = vhA;  *(ushort4*)&b1hi[base + 4] = vhB;
        *(ushort4*)&b1lo[base] = vlA;  *(ushort4*)&b1lo[base + 4] = vlB;
    }
}

// -------- FUSED 2-branch H=1 aggregation ----------------------------------
template <int DB, int ACT0, int ACT1, int SPLITOUT>
__global__ __launch_bounds__(256) void k_agg1x2(const int* __restrict__ rowptr,
                                                const int* __restrict__ csr,
                                                const float* __restrict__ el2,
                                                const float* __restrict__ er2,
                                                const _Float16* __restrict__ featC,
                                                unsigned short* __restrict__ o0hi,
                                                unsigned short* __restrict__ o0lo,
                                                unsigned short* __restrict__ o1hi,
                                                unsigned short* __restrict__ o1lo,
                                                float* __restrict__ ofp0,
                                                float* __restrict__ ofp1, int n) {
    __shared__ int   s_off[4][64];
    __shared__ float s_ex0[4][64];
    __shared__ float s_ex1[4][64];
    int w = threadIdx.x >> 6;
    int i = blockIdx.x * 4 + w;
    int lane = threadIdx.x & 63;
    if (i >= n) return;
    int s0 = rowptr[i], s1 = rowptr[i + 1];
    int deg = s1 - s0;
    float2 erp = *(const float2*)&er2[i * 2];
    bool act = lane < DB;
    int b = (lane >= (DB / 2)) ? 1 : 0;
    int loc = lane - b * (DB / 2);
    const char* featLane = (const char*)featC + lane * 4;
    const int ROWB = 4 * DB;

    float den0 = 0.f, den1 = 0.f, acc0 = 0.f, acc1 = 0.f;
    float m0 = -INFINITY, m1 = -INFINITY;

    auto fma_chunk = [&](int cnt) {
        const float* exr = b ? s_ex1[w] : s_ex0[w];
        int j = 0;
        for (; j + 4 <= cnt; j += 4) {
            int4   oj = *(const int4*)&s_off[w][j];
            float4 xj = *(const float4*)&exr[j];
            unsigned u0 = act ? *(const unsigned*)(featLane + oj.x) : 0u;
            unsigned u1 = act ? *(const unsigned*)(featLane + oj.y) : 0u;
            unsigned u2 = act ? *(const unsigned*)(featLane + oj.z) : 0u;
            unsigned u3 = act ? *(const unsigned*)(featLane + oj.w) : 0u;
            FMAMIX_LO(acc0, u0, xj.x); FMAMIX_HI(acc1, u0, xj.x);
            FMAMIX_LO(acc0, u1, xj.y); FMAMIX_HI(acc1, u1, xj.y);
            FMAMIX_LO(acc0, u2, xj.z); FMAMIX_HI(acc1, u2, xj.z);
            FMAMIX_LO(acc0, u3, xj.w); FMAMIX_HI(acc1, u3, xj.w);
        }
        for (; j < cnt; ++j) {
            unsigned u0 = act ? *(const unsigned*)(featLane + s_off[w][j]) : 0u;
            float x = exr[j];
            FMAMIX_LO(acc0, u0, x); FMAMIX_HI(acc1, u0, x);
        }
    };

    for (int c = s0; c < s1; c += 64) {
        int e = c + lane;
        bool val = e < s1;
        int s = 0;
        float2 elp = {0.f, 0.f};
        if (val) {
            s = csr[e];
            elp = *(const float2*)&el2[s * 2];
        }
        float v0 = val ? lrelu(elp.x + erp.x) : -INFINITY;
        float v1 = val ? lrelu(elp.y + erp.y) : -INFINITY;
        float cm0 = v0, cm1 = v1;
        #pragma unroll
        for (int off = 32; off; off >>= 1) {
            cm0 = fmaxf(cm0, __shfl_xor(cm0, off));
            cm1 = fmaxf(cm1, __shfl_xor(cm1, off));
        }
        float mn0 = fmaxf(m0, cm0), mn1 = fmaxf(m1, cm1);
        float sc0 = __expf(m0 - mn0), sc1 = __expf(m1 - mn1);
        m0 = mn0; m1 = mn1;
        float ex0 = val ? __expf(v0 - mn0) : 0.f;
        float ex1 = val ? __expf(v1 - mn1) : 0.f;
        den0 = den0 * sc0 + ex0;
        den1 = den1 * sc1 + ex1;
        float scl = b ? sc1 : sc0;
        acc0 *= scl; acc1 *= scl;
        s_off[w][lane] = s * ROWB;
        s_ex0[w][lane] = ex0;
        s_ex1[w][lane] = ex1;
        fma_chunk(min(64, s1 - c));
    }
    #pragma unroll
    for (int off = 32; off; off >>= 1) {
        den0 += __shfl_xor(den0, off);
        den1 += __shfl_xor(den1, off);
    }
    float d = fmaxf(b ? den1 : den0, 1e-9f);

    float o0 = (deg > 0) ? acc0 / d : 0.f;
    float o1 = (deg > 0) ? acc1 / d : 0.f;
    int actflag = b ? ACT1 : ACT0;
    if (actflag) {
        o0 = o0 > 0.f ? o0 : (__expf(o0) - 1.f);
        o1 = o1 > 0.f ? o1 : (__expf(o1) - 1.f);
    }
    if (act) {
        if (SPLITOUT) {
            unsigned short h0, l0, h1, l1;
            split_bf(o0, h0, l0);
            split_bf(o1, h1, l1);
            ushort2 vh = {h0, h1}, vl = {l0, l1};
            if (b == 0) {
                *(ushort2*)&o0hi[(size_t)i * DB + 2 * loc] = vh;
                *(ushort2*)&o0lo[(size_t)i * DB + 2 * loc] = vl;
            } else {
                *(ushort2*)&o1hi[(size_t)i * DB + 2 * loc] = vh;
                *(ushort2*)&o1lo[(size_t)i * DB + 2 * loc] = vl;
            }
        } else {
            float2 vo = {o0, o1};
            if (b == 0) *(float2*)&ofp0[(size_t)i * DB + 2 * loc] = vo;
            else        *(float2*)&ofp1[(size_t)i * DB + 2 * loc] = vo;
        }
    }
}

// ---------------- launch ----------------

extern "C" void kernel_launch(void* const* d_in, const int* in_sizes, int n_in,
                              void* d_out, int out_size, void* d_ws, size_t ws_size,
                              hipStream_t stream) {
    const float* x    = (const float*)d_in[0];
    const int*   src  = (const int*)d_in[1];
    const int*   dst  = (const int*)d_in[2];
    const float* W00  = (const float*)d_in[3];
    const float* a00l = (const float*)d_in[4];
    const float* a00r = (const float*)d_in[5];
    const float* W01  = (const float*)d_in[6];
    const float* a01l = (const float*)d_in[7];
    const float* a01r = (const float*)d_in[8];
    const float* W0f  = (const float*)d_in[9];
    const float* a0fl = (const float*)d_in[10];
    const float* a0fr = (const float*)d_in[11];
    const float* W10  = (const float*)d_in[12];
    const float* a10l = (const float*)d_in[13];
    const float* a10r = (const float*)d_in[14];
    const float* W1f  = (const float*)d_in[15];
    const float* a1fl = (const float*)d_in[16];
    const float* a1fr = (const float*)d_in[17];
    const float* W1o  = (const float*)d_in[18];
    const float* a1ol = (const float*)d_in[19];
    const float* a1or = (const float*)d_in[20];
    float* out = (float*)d_out;

    const int n = in_sizes[0] / 256;  // 50000
    const int e = in_sizes[1];        // 800000
    const int C = 40;

    char* p = (char*)d_ws;
    auto alloc = [&](size_t bytes) -> void* {
        void* r = (void*)p;
        p += (bytes + 255) & ~(size_t)255;
        return r;
    };
    int*   deg     = (int*)alloc((size_t)n * 4);
    int*   tmp     = (int*)alloc((size_t)n * 4);
    int*   bsum    = (int*)alloc(64 * 4);
    int*   rowptr  = (int*)alloc((size_t)(n + 1) * 4);
    int*   cursor  = (int*)alloc((size_t)n * 4);
    int*   csr     = (int*)alloc((size_t)e * 4);
    float* el8     = (float*)alloc((size_t)n * 8 * 4);
    float* er8     = (float*)alloc((size_t)n * 8 * 4);
    _Float16* featC = (_Float16*)alloc((size_t)n * 512 * 2 + 256);
    unsigned short* xhi = (unsigned short*)alloc((size_t)n * 256 * 2);  // x split; reused for branch1 feats
    unsigned short* xlo = (unsigned short*)alloc((size_t)n * 256 * 2);
    unsigned short* hhi = (unsigned short*)alloc((size_t)n * 256 * 2);  // branch0 feats
    unsigned short* hlo = (unsigned short*)alloc((size_t)n * 256 * 2);
    unsigned short* W00h = (unsigned short*)alloc(256 * 256 * 2);
    unsigned short* W00l = (unsigned short*)alloc(256 * 256 * 2);
    unsigned short* W01h = (unsigned short*)alloc(256 * 64 * 2);
    unsigned short* W01l = (unsigned short*)alloc(256 * 64 * 2);
    unsigned short* W0fh = (unsigned short*)alloc(64 * 40 * 2);
    unsigned short* W0fl = (unsigned short*)alloc(64 * 40 * 2);
    unsigned short* W10h = (unsigned short*)alloc(256 * 256 * 2);
    unsigned short* W10l = (unsigned short*)alloc(256 * 256 * 2);
    unsigned short* W1fh = (unsigned short*)alloc(256 * 64 * 2);
    unsigned short* W1fl = (unsigned short*)alloc(256 * 64 * 2);
    unsigned short* W1oh = (unsigned short*)alloc(64 * 40 * 2);
    unsigned short* W1ol = (unsigned short*)alloc(64 * 40 * 2);

    // ---- CSR build ----
    hipMemsetAsync(deg, 0, (size_t)n * 4, stream);
    k_hist<<<(e + 255) / 256, 256, 0, stream>>>(dst, deg, e);
    int nb = (n + 1023) / 1024;
    k_scan1<<<nb, 1024, 0, stream>>>(deg, tmp, bsum, n);
    k_scan2<<<1, 1, 0, stream>>>(bsum, nb);
    k_scan3<<<(n + 255) / 256, 256, 0, stream>>>(deg, tmp, bsum, rowptr, cursor, n);
    k_scatter<<<(e + 255) / 256, 256, 0, stream>>>(src, dst, cursor, csr, e);

    // ---- casts ----
    int nel = n * 256;
    k_castx<<<(nel / 4 + 255) / 256, 256, 0, stream>>>(x, xhi, xlo, nel / 4);
    {
        WSeg s0 = {W00, W00h, W00l, 256, 256, 256 * 256};
        WSeg s1 = {W10, W10h, W10l, 256, 256, 256 * 256};
        WSeg s2 = {W01, W01h, W01l, 256, 64, 256 * 64};
        WSeg s3 = {W1f, W1fh, W1fl, 256, 64, 256 * 64};
        WSeg s4 = {W0f, W0fh, W0fl, 64, 40, 64 * 40};
        WSeg s5 = {W1o, W1oh, W1ol, 64, 40, 64 * 40};
        int tot = 2 * 65536 + 2 * 16384 + 2 * 2560;
        k_castw_all<<<(tot + 255) / 256, 256, 0, stream>>>(s0, s1, s2, s3, s4, s5);
    }

    int gw1 = (n + 3) / 4;

    // ---- fused layer 0 (both branches), attn fused into GEMM epilogue ----
    gemm_split(xhi, xlo, W00h, W00l, featC,       n, 256, 256, 512,
               a00l, a00r, el8, er8, 0, stream);
    gemm_split(xhi, xlo, W10h, W10l, featC + 256, n, 256, 256, 512,
               a10l, a10r, el8, er8, 1, stream);
    // b0 h -> hhi/hlo, b1 h -> xhi/xlo (x split dead after L0 GEMMs)
    k_agg4x2<<<gw1, 256, 0, stream>>>(rowptr, csr, el8, er8, featC, hhi, hlo, xhi, xlo, n);

    // ---- fused mid layer (b0 L1 elu | b1 encoder-final no-act) ----
    gemm_split(hhi, hlo, W01h, W01l, featC,      n, 64, 256, 128,
               a01l, a01r, el8, er8, 0, stream);
    gemm_split(xhi, xlo, W1fh, W1fl, featC + 64, n, 64, 256, 128,
               a1fl, a1fr, el8, er8, 1, stream);
    k_agg1x2<64, 1, 0, 1><<<gw1, 256, 0, stream>>>(rowptr, csr, el8, er8, featC,
                                                   hhi, hlo, xhi, xlo, nullptr, nullptr, n);

    // ---- fused final layer (b0 no-act | b1 elu) ----
    gemm_split(hhi, hlo, W0fh, W0fl, featC,      n, C, 64, 80,
               a0fl, a0fr, el8, er8, 0, stream);
    gemm_split(xhi, xlo, W1oh, W1ol, featC + 40, n, C, 64, 80,
               a1ol, a1or, el8, er8, 1, stream);
    k_agg1x2<40, 0, 1, 0><<<gw1, 256, 0, stream>>>(rowptr, csr, el8, er8, featC,
                                                   nullptr, nullptr, nullptr, nullptr,
                                                   out, out + (size_t)n * C, n);
}

// Round 7
// 535.472 us; speedup vs baseline: 1.3806x; 1.0898x over previous
//
#include <hip/hip_runtime.h>
#include <math.h>

typedef __attribute__((ext_vector_type(8))) short bf16x8;
typedef __attribute__((ext_vector_type(4))) float f32x4;

// f32 += f16(lo/hi half of packed dword) * f32  -- exact, single VOP3P instr
#define FMAMIX_LO(acc, pk, s) \
    asm("v_fma_mix_f32 %0, %1, %2, %0 op_sel:[0,0,0] op_sel_hi:[1,0,0]" \
        : "+v"(acc) : "v"(pk), "v"(s))
#define FMAMIX_HI(acc, pk, s) \
    asm("v_fma_mix_f32 %0, %1, %2, %0 op_sel:[1,0,0] op_sel_hi:[1,0,0]" \
        : "+v"(acc) : "v"(pk), "v"(s))

__device__ __forceinline__ unsigned short f2bf(float f) {
    unsigned int u = __float_as_uint(f);
    unsigned int r = (u + 0x7FFF + ((u >> 16) & 1)) >> 16;  // RNE
    return (unsigned short)r;
}
__device__ __forceinline__ float bf2f(unsigned short h) {
    return __uint_as_float((unsigned int)h << 16);
}
__device__ __forceinline__ void split_bf(float x, unsigned short& hi, unsigned short& lo) {
    hi = f2bf(x);
    lo = f2bf(x - bf2f(hi));
}

// ---------------- CSR build ----------------

__global__ void k_hist(const int* __restrict__ dst, int* __restrict__ deg, int e) {
    int t = blockIdx.x * 256 + threadIdx.x;
    if (t < e) atomicAdd(&deg[dst[t]], 1);
}

__global__ void k_scan1(const int* __restrict__ deg, int* __restrict__ tmp,
                        int* __restrict__ bsum, int n) {
    __shared__ int s[1024];
    int t = threadIdx.x;
    int g = blockIdx.x * 1024 + t;
    int v = (g < n) ? deg[g] : 0;
    s[t] = v;
    __syncthreads();
    for (int off = 1; off < 1024; off <<= 1) {
        int u = (t >= off) ? s[t - off] : 0;
        __syncthreads();
        s[t] += u;
        __syncthreads();
    }
    if (g < n) tmp[g] = s[t];
    if (t == 1023) bsum[blockIdx.x] = s[t];
}

// 64-lane shfl scan (nb <= 64) -> exclusive block sums; replaces 1-thread serial
__global__ void k_scan2(int* bsum, int nb) {
    int lane = threadIdx.x;
    int orig = (lane < nb) ? bsum[lane] : 0;
    int v = orig;
    #pragma unroll
    for (int off = 1; off < 64; off <<= 1) {
        int u = __shfl_up(v, off);
        if (lane >= off) v += u;
    }
    if (lane < nb) bsum[lane] = v - orig;
}

__global__ void k_scan3(const int* __restrict__ deg, const int* __restrict__ tmp,
                        const int* __restrict__ bsum, int* __restrict__ rowptr,
                        int* __restrict__ cursor, int n) {
    int g = blockIdx.x * 256 + threadIdx.x;
    if (g < n) {
        int incl = tmp[g] + bsum[g >> 10];
        rowptr[g + 1] = incl;
        cursor[g] = incl - deg[g];
        if (g == 0) rowptr[0] = 0;
    }
}

__global__ void k_scatter(const int* __restrict__ src, const int* __restrict__ dst,
                          int* __restrict__ cursor, int* __restrict__ csr, int e) {
    int t = blockIdx.x * 256 + threadIdx.x;
    if (t < e) {
        int d = dst[t];
        int pos = atomicAdd(&cursor[d], 1);
        csr[pos] = src[t];
    }
}

// ---------------- weight cast (one dispatch, all 6 matrices) ----------------

struct WSeg { const float* W; unsigned short* Wh; unsigned short* Wl; int K; int N; int cnt; };
__global__ void k_castw_all(WSeg s0, WSeg s1, WSeg s2, WSeg s3, WSeg s4, WSeg s5) {
    int t = blockIdx.x * 256 + threadIdx.x;
    WSeg sg;
    if      (t < s0.cnt) { sg = s0; }
    else if ((t -= s0.cnt) < s1.cnt) { sg = s1; }
    else if ((t -= s1.cnt) < s2.cnt) { sg = s2; }
    else if ((t -= s2.cnt) < s3.cnt) { sg = s3; }
    else if ((t -= s3.cnt) < s4.cnt) { sg = s4; }
    else if ((t -= s4.cnt) < s5.cnt) { sg = s5; }
    else return;
    int k = t / sg.N, n = t - k * sg.N;
    unsigned short h, l;
    split_bf(sg.W[t], h, l);
    sg.Wh[n * sg.K + k] = h;
    sg.Wl[n * sg.K + k] = l;
}

#define LDP 40

// ------- L0 GEMM: fp32 A split on the fly, BOTH branches in one dispatch ---
// blockIdx.x < nwg -> branch 0 (B0, a0), else branch 1. Attn epilogue fused.
__global__ __launch_bounds__(256) void k_gemm128f(const float* __restrict__ X,
                                                  const unsigned short* __restrict__ B0h,
                                                  const unsigned short* __restrict__ B0l,
                                                  const unsigned short* __restrict__ B1h,
                                                  const unsigned short* __restrict__ B1l,
                                                  _Float16* __restrict__ C,   // ldc=512
                                                  int M, int K,
                                                  const float* __restrict__ a0l,
                                                  const float* __restrict__ a0r,
                                                  const float* __restrict__ a1l,
                                                  const float* __restrict__ a1r,
                                                  float* __restrict__ el8,
                                                  float* __restrict__ er8) {
    int Mb = (M + 127) >> 7;
    int nwg = Mb * 2;
    int v = blockIdx.x;
    int bsel = (v >= nwg) ? 1 : 0;
    v -= bsel * nwg;
    int q = nwg >> 3, r = nwg & 7;
    int xcd = v & 7, idx = v >> 3;
    int wg = (xcd < r ? xcd * (q + 1) : r * (q + 1) + (xcd - r) * q) + idx;
    int bx = wg >> 1, by = wg & 1;
    int row0 = bx * 128, col0 = by * 128;
    const unsigned short* Bh = bsel ? B1h : B0h;
    const unsigned short* Bl = bsel ? B1l : B0l;
    const float* alp = bsel ? a1l : a0l;
    const float* arp = bsel ? a1r : a0r;
    _Float16* Cb = C + bsel * 256;

    __shared__ unsigned short Ash[128 * LDP];
    __shared__ unsigned short Asl[128 * LDP];
    __shared__ unsigned short Bsh[128 * LDP];
    __shared__ unsigned short Bsl[128 * LDP];

    int t = threadIdx.x;
    int w = t >> 6, lane = t & 63;
    int wr = w >> 1, wc = w & 1;
    int lrow = lane & 15, kgrp = (lane >> 4) * 8;
    int trow = t >> 1, tcol = (t & 1) * 16;

    f32x4 acc[4][4];
    #pragma unroll
    for (int mt = 0; mt < 4; ++mt)
        #pragma unroll
        for (int nt = 0; nt < 4; ++nt)
            acc[mt][nt] = (f32x4){0.f, 0.f, 0.f, 0.f};

    for (int k0 = 0; k0 < K; k0 += 32) {
        uint4 ah0 = {0u,0u,0u,0u}, ah1 = {0u,0u,0u,0u};
        uint4 av0 = {0u,0u,0u,0u}, av1 = {0u,0u,0u,0u};
        uint4 b0 = {0u,0u,0u,0u}, b1 = {0u,0u,0u,0u};
        uint4 m0 = {0u,0u,0u,0u}, m1 = {0u,0u,0u,0u};
        int gr = row0 + trow;
        if (gr < M) {
            const float* px = X + (size_t)gr * K + k0 + tcol;
            float4 f0 = *(const float4*)px;
            float4 f1 = *(const float4*)(px + 4);
            float4 f2 = *(const float4*)(px + 8);
            float4 f3 = *(const float4*)(px + 12);
            float ff[16] = {f0.x, f0.y, f0.z, f0.w, f1.x, f1.y, f1.z, f1.w,
                            f2.x, f2.y, f2.z, f2.w, f3.x, f3.y, f3.z, f3.w};
            unsigned hp[8], lp[8];
            #pragma unroll
            for (int j = 0; j < 8; ++j) {
                unsigned short ha, la, hb, lb;
                split_bf(ff[2 * j], ha, la);
                split_bf(ff[2 * j + 1], hb, lb);
                hp[j] = (unsigned)ha | ((unsigned)hb << 16);
                lp[j] = (unsigned)la | ((unsigned)lb << 16);
            }
            ah0 = (uint4){hp[0], hp[1], hp[2], hp[3]};
            ah1 = (uint4){hp[4], hp[5], hp[6], hp[7]};
            av0 = (uint4){lp[0], lp[1], lp[2], lp[3]};
            av1 = (uint4){lp[4], lp[5], lp[6], lp[7]};
        }
        int gc = col0 + trow;
        {
            const unsigned short* pb = Bh + (size_t)gc * K + k0 + tcol;
            const unsigned short* pm = Bl + (size_t)gc * K + k0 + tcol;
            b0 = *(const uint4*)pb;       b1 = *(const uint4*)(pb + 8);
            m0 = *(const uint4*)pm;       m1 = *(const uint4*)(pm + 8);
        }
        __syncthreads();
        *(uint4*)&Ash[trow * LDP + tcol]     = ah0;
        *(uint4*)&Ash[trow * LDP + tcol + 8] = ah1;
        *(uint4*)&Asl[trow * LDP + tcol]     = av0;
        *(uint4*)&Asl[trow * LDP + tcol + 8] = av1;
        *(uint4*)&Bsh[trow * LDP + tcol]     = b0;
        *(uint4*)&Bsh[trow * LDP + tcol + 8] = b1;
        *(uint4*)&Bsl[trow * LDP + tcol]     = m0;
        *(uint4*)&Bsl[trow * LDP + tcol + 8] = m1;
        __syncthreads();

        bf16x8 vbh[4], vbl[4];
        #pragma unroll
        for (int nt = 0; nt < 4; ++nt) {
            vbh[nt] = *(const bf16x8*)&Bsh[(wc * 64 + nt * 16 + lrow) * LDP + kgrp];
            vbl[nt] = *(const bf16x8*)&Bsl[(wc * 64 + nt * 16 + lrow) * LDP + kgrp];
        }
        #pragma unroll
        for (int mt = 0; mt < 4; ++mt) {
            bf16x8 vah = *(const bf16x8*)&Ash[(wr * 64 + mt * 16 + lrow) * LDP + kgrp];
            bf16x8 val = *(const bf16x8*)&Asl[(wr * 64 + mt * 16 + lrow) * LDP + kgrp];
            #pragma unroll
            for (int nt = 0; nt < 4; ++nt) {
                acc[mt][nt] = __builtin_amdgcn_mfma_f32_16x16x32_bf16(vah, vbh[nt], acc[mt][nt], 0, 0, 0);
                acc[mt][nt] = __builtin_amdgcn_mfma_f32_16x16x32_bf16(val, vbh[nt], acc[mt][nt], 0, 0, 0);
                acc[mt][nt] = __builtin_amdgcn_mfma_f32_16x16x32_bf16(vah, vbl[nt], acc[mt][nt], 0, 0, 0);
            }
        }
    }

    int orow = (lane >> 4) * 4;
    #pragma unroll
    for (int mt = 0; mt < 4; ++mt) {
        #pragma unroll
        for (int nt = 0; nt < 4; ++nt) {
            int oc = col0 + wc * 64 + nt * 16 + lrow;
            #pragma unroll
            for (int rr = 0; rr < 4; ++rr) {
                int m = row0 + wr * 64 + mt * 16 + orow + rr;
                if (m < M) Cb[(size_t)m * 512 + oc] = (_Float16)acc[mt][nt][rr];
            }
        }
    }

    // ---- fused per-head attn epilogue (head = by*2+wc) ----
    int h = by * 2 + wc;
    float alv[4], arv[4];
    #pragma unroll
    for (int nt = 0; nt < 4; ++nt) {
        int cidx = nt * 16 + lrow;
        alv[nt] = alp[h * 64 + cidx];
        arv[nt] = arp[h * 64 + cidx];
    }
    #pragma unroll
    for (int mt = 0; mt < 4; ++mt) {
        #pragma unroll
        for (int rr = 0; rr < 4; ++rr) {
            float pl = 0.f, pr = 0.f;
            #pragma unroll
            for (int nt = 0; nt < 4; ++nt) {
                pl = fmaf(acc[mt][nt][rr], alv[nt], pl);
                pr = fmaf(acc[mt][nt][rr], arv[nt], pr);
            }
            #pragma unroll
            for (int off = 1; off < 16; off <<= 1) {
                pl += __shfl_xor(pl, off);
                pr += __shfl_xor(pr, off);
            }
            int m = row0 + wr * 64 + mt * 16 + orow + rr;
            if (lrow == 0 && m < M) {
                el8[m * 8 + h * 2 + bsel] = pl;
                er8[m * 8 + h * 2 + bsel] = pr;
            }
        }
    }
}

// ------- 64x64-tile GEMM, BOTH branches in one dispatch (bsel=blockIdx.y) --
// H=1 attn epilogue fused (cross-wave LDS reduce).
__global__ __launch_bounds__(256) void k_gemm_split2(const unsigned short* __restrict__ A0hi,
                                                     const unsigned short* __restrict__ A0lo,
                                                     const unsigned short* __restrict__ B0hp,
                                                     const unsigned short* __restrict__ B0lp,
                                                     const unsigned short* __restrict__ A1hi,
                                                     const unsigned short* __restrict__ A1lo,
                                                     const unsigned short* __restrict__ B1hp,
                                                     const unsigned short* __restrict__ B1lp,
                                                     _Float16* __restrict__ C0,
                                                     _Float16* __restrict__ C1,
                                                     int M, int Ncol, int K, int ldc,
                                                     const float* __restrict__ a0lp,
                                                     const float* __restrict__ a0rp,
                                                     const float* __restrict__ a1lp,
                                                     const float* __restrict__ a1rp,
                                                     float* __restrict__ el2,
                                                     float* __restrict__ er2) {
    int bx = blockIdx.x;
    int bsel = blockIdx.y;
    const unsigned short* Ahi = bsel ? A1hi : A0hi;
    const unsigned short* Alo = bsel ? A1lo : A0lo;
    const unsigned short* Bhi = bsel ? B1hp : B0hp;
    const unsigned short* Blo = bsel ? B1lp : B0lp;
    const float* al = bsel ? a1lp : a0lp;
    const float* ar = bsel ? a1rp : a0rp;
    _Float16* C = bsel ? C1 : C0;

    __shared__ unsigned short Ash[64 * LDP];
    __shared__ unsigned short Asl[64 * LDP];
    __shared__ unsigned short Bsh[64 * LDP];
    __shared__ unsigned short Bsl[64 * LDP];
    int t = threadIdx.x;
    int w = t >> 6, lane = t & 63;
    int lrow = lane & 15, kgrp = (lane >> 4) * 8;
    int row0 = bx * 64;
    int trow = t >> 2, tcol = (t & 3) * 8;

    f32x4 acc[4] = {{0.f, 0.f, 0.f, 0.f}, {0.f, 0.f, 0.f, 0.f},
                    {0.f, 0.f, 0.f, 0.f}, {0.f, 0.f, 0.f, 0.f}};

    for (int k0 = 0; k0 < K; k0 += 32) {
        uint4 ah = {0u,0u,0u,0u}, al4 = {0u,0u,0u,0u};
        uint4 bh = {0u,0u,0u,0u}, bl4 = {0u,0u,0u,0u};
        int gr = row0 + trow;
        if (gr < M) {
            ah  = *(const uint4*)(Ahi + (size_t)gr * K + k0 + tcol);
            al4 = *(const uint4*)(Alo + (size_t)gr * K + k0 + tcol);
        }
        if (trow < Ncol) {
            bh  = *(const uint4*)(Bhi + (size_t)trow * K + k0 + tcol);
            bl4 = *(const uint4*)(Blo + (size_t)trow * K + k0 + tcol);
        }
        __syncthreads();
        *(uint4*)&Ash[trow * LDP + tcol] = ah;
        *(uint4*)&Asl[trow * LDP + tcol] = al4;
        *(uint4*)&Bsh[trow * LDP + tcol] = bh;
        *(uint4*)&Bsl[trow * LDP + tcol] = bl4;
        __syncthreads();
        bf16x8 vbh = *(const bf16x8*)&Bsh[(w * 16 + lrow) * LDP + kgrp];
        bf16x8 vbl = *(const bf16x8*)&Bsl[(w * 16 + lrow) * LDP + kgrp];
        #pragma unroll
        for (int mt = 0; mt < 4; ++mt) {
            bf16x8 vah = *(const bf16x8*)&Ash[(mt * 16 + lrow) * LDP + kgrp];
            bf16x8 val = *(const bf16x8*)&Asl[(mt * 16 + lrow) * LDP + kgrp];
            acc[mt] = __builtin_amdgcn_mfma_f32_16x16x32_bf16(vah, vbh, acc[mt], 0, 0, 0);
            acc[mt] = __builtin_amdgcn_mfma_f32_16x16x32_bf16(val, vbh, acc[mt], 0, 0, 0);
            acc[mt] = __builtin_amdgcn_mfma_f32_16x16x32_bf16(vah, vbl, acc[mt], 0, 0, 0);
        }
    }

    int ocol = w * 16 + lrow;
    int orow = (lane >> 4) * 4;
    if (ocol < Ncol) {
        #pragma unroll
        for (int mt = 0; mt < 4; ++mt) {
            #pragma unroll
            for (int r = 0; r < 4; ++r) {
                int m = row0 + mt * 16 + orow + r;
                if (m < M) C[(size_t)m * ldc + ocol] = (_Float16)acc[mt][r];
            }
        }
    }

    // ---- fused H=1 attn epilogue ----
    float alv = (ocol < Ncol) ? al[ocol] : 0.f;
    float arv = (ocol < Ncol) ? ar[ocol] : 0.f;
    __syncthreads();
    float* Pl = (float*)Ash;   // [4 waves][64 rows]
    float* Pr = (float*)Bsh;
    #pragma unroll
    for (int mt = 0; mt < 4; ++mt) {
        #pragma unroll
        for (int r = 0; r < 4; ++r) {
            float pl = acc[mt][r] * alv;
            float pr = acc[mt][r] * arv;
            #pragma unroll
            for (int off = 1; off < 16; off <<= 1) {
                pl += __shfl_xor(pl, off);
                pr += __shfl_xor(pr, off);
            }
            if (lrow == 0) {
                int rloc = mt * 16 + orow + r;
                Pl[w * 64 + rloc] = pl;
                Pr[w * 64 + rloc] = pr;
            }
        }
    }
    __syncthreads();
    if (t < 64) {
        int m = row0 + t;
        if (m < M) {
            float pl = Pl[t] + Pl[64 + t] + Pl[128 + t] + Pl[192 + t];
            float pr = Pr[t] + Pr[64 + t] + Pr[128 + t] + Pr[192 + t];
            el2[m * 2 + bsel] = pl;
            er2[m * 2 + bsel] = pr;
        }
    }
}

__device__ __forceinline__ float lrelu(float v) { return v > 0.f ? v : 0.2f * v; }

// -------- FUSED H=4 aggregation for BOTH branches: ONE WAVE per dst -------
#define A42_ISSUE(J) uint4 q##J = *(const uint4*)(featLane + ((size_t)(unsigned)__shfl(s, (J) << 2) << 10))
#define A42_CONS(J, X) \
    FMAMIX_LO(f0, q##J.x, X); FMAMIX_HI(f1, q##J.x, X); \
    FMAMIX_LO(f2, q##J.y, X); FMAMIX_HI(f3, q##J.y, X); \
    FMAMIX_LO(f4, q##J.z, X); FMAMIX_HI(f5, q##J.z, X); \
    FMAMIX_LO(f6, q##J.w, X); FMAMIX_HI(f7, q##J.w, X)

__global__ __launch_bounds__(256) void k_agg4x2(const int* __restrict__ rowptr,
                                                const int* __restrict__ csr,
                                                const float* __restrict__ el8,
                                                const float* __restrict__ er8,
                                                const _Float16* __restrict__ featC,
                                                unsigned short* __restrict__ b0hi,
                                                unsigned short* __restrict__ b0lo,
                                                unsigned short* __restrict__ b1hi,
                                                unsigned short* __restrict__ b1lo,
                                                int n) {
    __shared__ float s_ex[4][128];  // [wave][b*64 + h*16 + eidx]
    int w = threadIdx.x >> 6;
    int lane = threadIdx.x & 63;
    int i = blockIdx.x * 4 + w;
    if (i >= n) return;
    int s0 = rowptr[i], s1 = rowptr[i + 1];
    int deg = s1 - s0;
    int eidx = lane >> 2, h = lane & 3;     // exp-stage role
    int b = lane >> 5, hh = (lane >> 3) & 3; // FMA/output-stage role
    float2 erp = *(const float2*)&er8[i * 8 + h * 2];  // (b0, b1) for head h
    const char* featLane = (const char*)featC + (lane << 4);

    float den0 = 0.f, den1 = 0.f;
    float m0 = -INFINITY, m1 = -INFINITY;
    float f0 = 0.f, f1 = 0.f, f2 = 0.f, f3 = 0.f;
    float f4 = 0.f, f5 = 0.f, f6 = 0.f, f7 = 0.f;

    int e0 = s0 + eidx;
    int s = (e0 < s1) ? csr[e0] : 0;
    for (int c = s0; c < s1; c += 16) {
        bool val = (c + eidx < s1);
        float2 elp = *(const float2*)&el8[(s << 3) + h * 2];
        A42_ISSUE(0);  A42_ISSUE(1);  A42_ISSUE(2);  A42_ISSUE(3);
        A42_ISSUE(4);  A42_ISSUE(5);  A42_ISSUE(6);  A42_ISSUE(7);
        A42_ISSUE(8);  A42_ISSUE(9);  A42_ISSUE(10); A42_ISSUE(11);
        A42_ISSUE(12); A42_ISSUE(13); A42_ISSUE(14); A42_ISSUE(15);
        int en = c + 16 + eidx;
        int sn = (en < s1) ? csr[en] : 0;
        float v0 = val ? lrelu(elp.x + erp.x) : -INFINITY;
        float v1 = val ? lrelu(elp.y + erp.y) : -INFINITY;
        float cm0 = v0, cm1 = v1;
        #pragma unroll
        for (int off = 4; off < 64; off <<= 1) {
            cm0 = fmaxf(cm0, __shfl_xor(cm0, off));
            cm1 = fmaxf(cm1, __shfl_xor(cm1, off));
        }
        float mn0 = fmaxf(m0, cm0), mn1 = fmaxf(m1, cm1);
        float sc0 = __expf(m0 - mn0), sc1 = __expf(m1 - mn1);
        m0 = mn0; m1 = mn1;
        float ex0 = val ? __expf(v0 - mn0) : 0.f;
        float ex1 = val ? __expf(v1 - mn1) : 0.f;
        den0 = den0 * sc0 + ex0;
        den1 = den1 * sc1 + ex1;
        s_ex[w][(h << 4) + eidx] = ex0;
        s_ex[w][64 + (h << 4) + eidx] = ex1;
        float sb0 = __shfl(sc0, hh), sb1 = __shfl(sc1, hh);
        float scl = (lane < 32) ? sb0 : sb1;
        f0 *= scl; f1 *= scl; f2 *= scl; f3 *= scl;
        f4 *= scl; f5 *= scl; f6 *= scl; f7 *= scl;
        const float* exrow = &s_ex[w][(b << 6) + (hh << 4)];
        float4 x0 = *(const float4*)&exrow[0];
        float4 x1 = *(const float4*)&exrow[4];
        float4 x2 = *(const float4*)&exrow[8];
        float4 x3 = *(const float4*)&exrow[12];
        A42_CONS(0, x0.x);  A42_CONS(1, x0.y);  A42_CONS(2, x0.z);  A42_CONS(3, x0.w);
        A42_CONS(4, x1.x);  A42_CONS(5, x1.y);  A42_CONS(6, x1.z);  A42_CONS(7, x1.w);
        A42_CONS(8, x2.x);  A42_CONS(9, x2.y);  A42_CONS(10, x2.z); A42_CONS(11, x2.w);
        A42_CONS(12, x3.x); A42_CONS(13, x3.y); A42_CONS(14, x3.z); A42_CONS(15, x3.w);
        s = sn;
    }

    #pragma unroll
    for (int off = 4; off < 64; off <<= 1) {
        den0 += __shfl_xor(den0, off);
        den1 += __shfl_xor(den1, off);
    }
    float db0 = __shfl(den0, hh), db1 = __shfl(den1, hh);
    float d = fmaxf((lane < 32) ? db0 : db1, 1e-9f);

    float o0 = (deg > 0) ? f0 / d : 0.f;
    float o1 = (deg > 0) ? f1 / d : 0.f;
    float o2 = (deg > 0) ? f2 / d : 0.f;
    float o3 = (deg > 0) ? f3 / d : 0.f;
    float o4 = (deg > 0) ? f4 / d : 0.f;
    float o5 = (deg > 0) ? f5 / d : 0.f;
    float o6 = (deg > 0) ? f6 / d : 0.f;
    float o7 = (deg > 0) ? f7 / d : 0.f;
    o0 = o0 > 0.f ? o0 : (__expf(o0) - 1.f);
    o1 = o1 > 0.f ? o1 : (__expf(o1) - 1.f);
    o2 = o2 > 0.f ? o2 : (__expf(o2) - 1.f);
    o3 = o3 > 0.f ? o3 : (__expf(o3) - 1.f);
    o4 = o4 > 0.f ? o4 : (__expf(o4) - 1.f);
    o5 = o5 > 0.f ? o5 : (__expf(o5) - 1.f);
    o6 = o6 > 0.f ? o6 : (__expf(o6) - 1.f);
    o7 = o7 > 0.f ? o7 : (__expf(o7) - 1.f);

    ushort4 vhA, vlA, vhB, vlB;
    split_bf(o0, vhA.x, vlA.x);
    split_bf(o1, vhA.y, vlA.y);
    split_bf(o2, vhA.z, vlA.z);
    split_bf(o3, vhA.w, vlA.w);
    split_bf(o4, vhB.x, vlB.x);
    split_bf(o5, vhB.y, vlB.y);
    split_bf(o6, vhB.z, vlB.z);
    split_bf(o7, vhB.w, vlB.w);
    size_t base = (size_t)i * 256 + ((lane & 31) << 3);
    if (lane < 32) {
        *(ushort4*)&b0hi[base] = vhA;  *(ushort4*)&b0hi[base + 4] = vhB;
        *(ushort4*)&b0lo[base] = vlA;  *(ushort4*)&b0lo[base + 4] = vlB;
    } else {
        *(ushort4*)&b1hi[base] = vhA;  *(ushort4*)&b1hi[base + 4] = vhB;
        *(ushort4*)&b1lo[base] = vlA;  *(ushort4*)&b1lo[base + 4] = vlB;
    }
}

// -------- FUSED 2-branch H=1 aggregation ----------------------------------
template <int DB, int ACT0, int ACT1, int SPLITOUT>
__global__ __launch_bounds__(256) void k_agg1x2(const int* __restrict__ rowptr,
                                                const int* __restrict__ csr,
                                                const float* __restrict__ el2,
                                                const float* __restrict__ er2,
                                                const _Float16* __restrict__ featC,
                                                unsigned short* __restrict__ o0hi,
                                                unsigned short* __restrict__ o0lo,
                                                unsigned short* __restrict__ o1hi,
                                                unsigned short* __restrict__ o1lo,
                                                float* __restrict__ ofp0,
                                                float* __restrict__ ofp1, int n) {
    __shared__ int   s_off[4][64];
    __shared__ float s_ex0[4][64];
    __shared__ float s_ex1[4][64];
    int w = threadIdx.x >> 6;
    int i = blockIdx.x * 4 + w;
    int lane = threadIdx.x & 63;
    if (i >= n) return;
    int s0 = rowptr[i], s1 = rowptr[i + 1];
    int deg = s1 - s0;
    float2 erp = *(const float2*)&er2[i * 2];
    bool act = lane < DB;
    int b = (lane >= (DB / 2)) ? 1 : 0;
    int loc = lane - b * (DB / 2);
    const char* featLane = (const char*)featC + lane * 4;
    const int ROWB = 4 * DB;

    float den0 = 0.f, den1 = 0.f, acc0 = 0.f, acc1 = 0.f;
    float m0 = -INFINITY, m1 = -INFINITY;

    auto fma_chunk = [&](int cnt) {
        const float* exr = b ? s_ex1[w] : s_ex0[w];
        int j = 0;
        for (; j + 4 <= cnt; j += 4) {
            int4   oj = *(const int4*)&s_off[w][j];
            float4 xj = *(const float4*)&exr[j];
            unsigned u0 = act ? *(const unsigned*)(featLane + oj.x) : 0u;
            unsigned u1 = act ? *(const unsigned*)(featLane + oj.y) : 0u;
            unsigned u2 = act ? *(const unsigned*)(featLane + oj.z) : 0u;
            unsigned u3 = act ? *(const unsigned*)(featLane + oj.w) : 0u;
            FMAMIX_LO(acc0, u0, xj.x); FMAMIX_HI(acc1, u0, xj.x);
            FMAMIX_LO(acc0, u1, xj.y); FMAMIX_HI(acc1, u1, xj.y);
            FMAMIX_LO(acc0, u2, xj.z); FMAMIX_HI(acc1, u2, xj.z);
            FMAMIX_LO(acc0, u3, xj.w); FMAMIX_HI(acc1, u3, xj.w);
        }
        for (; j < cnt; ++j) {
            unsigned u0 = act ? *(const unsigned*)(featLane + s_off[w][j]) : 0u;
            float x = exr[j];
            FMAMIX_LO(acc0, u0, x); FMAMIX_HI(acc1, u0, x);
        }
    };

    for (int c = s0; c < s1; c += 64) {
        int e = c + lane;
        bool val = e < s1;
        int s = 0;
        float2 elp = {0.f, 0.f};
        if (val) {
            s = csr[e];
            elp = *(const float2*)&el2[s * 2];
        }
        float v0 = val ? lrelu(elp.x + erp.x) : -INFINITY;
        float v1 = val ? lrelu(elp.y + erp.y) : -INFINITY;
        float cm0 = v0, cm1 = v1;
        #pragma unroll
        for (int off = 32; off; off >>= 1) {
            cm0 = fmaxf(cm0, __shfl_xor(cm0, off));
            cm1 = fmaxf(cm1, __shfl_xor(cm1, off));
        }
        float mn0 = fmaxf(m0, cm0), mn1 = fmaxf(m1, cm1);
        float sc0 = __expf(m0 - mn0), sc1 = __expf(m1 - mn1);
        m0 = mn0; m1 = mn1;
        float ex0 = val ? __expf(v0 - mn0) : 0.f;
        float ex1 = val ? __expf(v1 - mn1) : 0.f;
        den0 = den0 * sc0 + ex0;
        den1 = den1 * sc1 + ex1;
        float scl = b ? sc1 : sc0;
        acc0 *= scl; acc1 *= scl;
        s_off[w][lane] = s * ROWB;
        s_ex0[w][lane] = ex0;
        s_ex1[w][lane] = ex1;
        fma_chunk(min(64, s1 - c));
    }
    #pragma unroll
    for (int off = 32; off; off >>= 1) {
        den0 += __shfl_xor(den0, off);
        den1 += __shfl_xor(den1, off);
    }
    float d = fmaxf(b ? den1 : den0, 1e-9f);

    float o0 = (deg > 0) ? acc0 / d : 0.f;
    float o1 = (deg > 0) ? acc1 / d : 0.f;
    int actflag = b ? ACT1 : ACT0;
    if (actflag) {
        o0 = o0 > 0.f ? o0 : (__expf(o0) - 1.f);
        o1 = o1 > 0.f ? o1 : (__expf(o1) - 1.f);
    }
    if (act) {
        if (SPLITOUT) {
            unsigned short h0, l0, h1, l1;
            split_bf(o0, h0, l0);
            split_bf(o1, h1, l1);
            ushort2 vh = {h0, h1}, vl = {l0, l1};
            if (b == 0) {
                *(ushort2*)&o0hi[(size_t)i * DB + 2 * loc] = vh;
                *(ushort2*)&o0lo[(size_t)i * DB + 2 * loc] = vl;
            } else {
                *(ushort2*)&o1hi[(size_t)i * DB + 2 * loc] = vh;
                *(ushort2*)&o1lo[(size_t)i * DB + 2 * loc] = vl;
            }
        } else {
            float2 vo = {o0, o1};
            if (b == 0) *(float2*)&ofp0[(size_t)i * DB + 2 * loc] = vo;
            else        *(float2*)&ofp1[(size_t)i * DB + 2 * loc] = vo;
        }
    }
}

// ---------------- launch ----------------

extern "C" void kernel_launch(void* const* d_in, const int* in_sizes, int n_in,
                              void* d_out, int out_size, void* d_ws, size_t ws_size,
                              hipStream_t stream) {
    const float* x    = (const float*)d_in[0];
    const int*   src  = (const int*)d_in[1];
    const int*   dst  = (const int*)d_in[2];
    const float* W00  = (const float*)d_in[3];
    const float* a00l = (const float*)d_in[4];
    const float* a00r = (const float*)d_in[5];
    const float* W01  = (const float*)d_in[6];
    const float* a01l = (const float*)d_in[7];
    const float* a01r = (const float*)d_in[8];
    const float* W0f  = (const float*)d_in[9];
    const float* a0fl = (const float*)d_in[10];
    const float* a0fr = (const float*)d_in[11];
    const float* W10  = (const float*)d_in[12];
    const float* a10l = (const float*)d_in[13];
    const float* a10r = (const float*)d_in[14];
    const float* W1f  = (const float*)d_in[15];
    const float* a1fl = (const float*)d_in[16];
    const float* a1fr = (const float*)d_in[17];
    const float* W1o  = (const float*)d_in[18];
    const float* a1ol = (const float*)d_in[19];
    const float* a1or = (const float*)d_in[20];
    float* out = (float*)d_out;

    const int n = in_sizes[0] / 256;  // 50000
    const int e = in_sizes[1];        // 800000
    const int C = 40;

    char* p = (char*)d_ws;
    auto alloc = [&](size_t bytes) -> void* {
        void* r = (void*)p;
        p += (bytes + 255) & ~(size_t)255;
        return r;
    };
    int*   deg     = (int*)alloc((size_t)n * 4);
    int*   tmp     = (int*)alloc((size_t)n * 4);
    int*   bsum    = (int*)alloc(64 * 4);
    int*   rowptr  = (int*)alloc((size_t)(n + 1) * 4);
    int*   cursor  = (int*)alloc((size_t)n * 4);
    int*   csr     = (int*)alloc((size_t)e * 4);
    float* el8     = (float*)alloc((size_t)n * 8 * 4);
    float* er8     = (float*)alloc((size_t)n * 8 * 4);
    _Float16* featC = (_Float16*)alloc((size_t)n * 512 * 2 + 256);
    unsigned short* xhi = (unsigned short*)alloc((size_t)n * 256 * 2);  // branch1 feats
    unsigned short* xlo = (unsigned short*)alloc((size_t)n * 256 * 2);
    unsigned short* hhi = (unsigned short*)alloc((size_t)n * 256 * 2);  // branch0 feats
    unsigned short* hlo = (unsigned short*)alloc((size_t)n * 256 * 2);
    unsigned short* W00h = (unsigned short*)alloc(256 * 256 * 2);
    unsigned short* W00l = (unsigned short*)alloc(256 * 256 * 2);
    unsigned short* W01h = (unsigned short*)alloc(256 * 64 * 2);
    unsigned short* W01l = (unsigned short*)alloc(256 * 64 * 2);
    unsigned short* W0fh = (unsigned short*)alloc(64 * 40 * 2);
    unsigned short* W0fl = (unsigned short*)alloc(64 * 40 * 2);
    unsigned short* W10h = (unsigned short*)alloc(256 * 256 * 2);
    unsigned short* W10l = (unsigned short*)alloc(256 * 256 * 2);
    unsigned short* W1fh = (unsigned short*)alloc(256 * 64 * 2);
    unsigned short* W1fl = (unsigned short*)alloc(256 * 64 * 2);
    unsigned short* W1oh = (unsigned short*)alloc(64 * 40 * 2);
    unsigned short* W1ol = (unsigned short*)alloc(64 * 40 * 2);

    // ---- CSR build ----
    hipMemsetAsync(deg, 0, (size_t)n * 4, stream);
    k_hist<<<(e + 255) / 256, 256, 0, stream>>>(dst, deg, e);
    int nb = (n + 1023) / 1024;
    k_scan1<<<nb, 1024, 0, stream>>>(deg, tmp, bsum, n);
    k_scan2<<<1, 64, 0, stream>>>(bsum, nb);
    k_scan3<<<(n + 255) / 256, 256, 0, stream>>>(deg, tmp, bsum, rowptr, cursor, n);
    k_scatter<<<(e + 255) / 256, 256, 0, stream>>>(src, dst, cursor, csr, e);

    // ---- weight casts (one dispatch) ----
    {
        WSeg s0 = {W00, W00h, W00l, 256, 256, 256 * 256};
        WSeg s1 = {W10, W10h, W10l, 256, 256, 256 * 256};
        WSeg s2 = {W01, W01h, W01l, 256, 64, 256 * 64};
        WSeg s3 = {W1f, W1fh, W1fl, 256, 64, 256 * 64};
        WSeg s4 = {W0f, W0fh, W0fl, 64, 40, 64 * 40};
        WSeg s5 = {W1o, W1oh, W1ol, 64, 40, 64 * 40};
        int tot = 2 * 65536 + 2 * 16384 + 2 * 2560;
        k_castw_all<<<(tot + 255) / 256, 256, 0, stream>>>(s0, s1, s2, s3, s4, s5);
    }

    int gw1 = (n + 3) / 4;
    int Mb128 = (n + 127) / 128;

    // ---- fused layer 0: ONE dispatch, both branches, fp32 A split on the fly
    k_gemm128f<<<Mb128 * 2 * 2, 256, 0, stream>>>(x, W00h, W00l, W10h, W10l, featC,
                                                  n, 256, a00l, a00r, a10l, a10r,
                                                  el8, er8);
    // b0 h -> hhi/hlo, b1 h -> xhi/xlo
    k_agg4x2<<<gw1, 256, 0, stream>>>(rowptr, csr, el8, er8, featC, hhi, hlo, xhi, xlo, n);

    // ---- fused mid layer: ONE dispatch (b0 L1 | b1 encoder-final) ----
    {
        dim3 g((n + 63) / 64, 2);
        k_gemm_split2<<<g, 256, 0, stream>>>(hhi, hlo, W01h, W01l,
                                             xhi, xlo, W1fh, W1fl,
                                             featC, featC + 64,
                                             n, 64, 256, 128,
                                             a01l, a01r, a1fl, a1fr, el8, er8);
    }
    k_agg1x2<64, 1, 0, 1><<<gw1, 256, 0, stream>>>(rowptr, csr, el8, er8, featC,
                                                   hhi, hlo, xhi, xlo, nullptr, nullptr, n);

    // ---- fused final layer: ONE dispatch (b0 out | b1 out) ----
    {
        dim3 g((n + 63) / 64, 2);
        k_gemm_split2<<<g, 256, 0, stream>>>(hhi, hlo, W0fh, W0fl,
                                             xhi, xlo, W1oh, W1ol,
                                             featC, featC + 40,
                                             n, C, 64, 80,
                                             a0fl, a0fr, a1ol, a1or, el8, er8);
    }
    k_agg1x2<40, 0, 1, 0><<<gw1, 256, 0, stream>>>(rowptr, csr, el8, er8, featC,
                                                   nullptr, nullptr, nullptr, nullptr,
                                                   out, out + (size_t)n * C, n);
}